// Round 6
// baseline (5870.199 us; speedup 1.0000x reference)
//
#include <hip/hip_runtime.h>
#include <hip/hip_bf16.h>

typedef _Float16 f16;
typedef f16   f16x8 __attribute__((ext_vector_type(8)));
typedef short s16x8 __attribute__((ext_vector_type(8)));
typedef float f32x4 __attribute__((ext_vector_type(4)));
typedef unsigned short u16;

__device__ __forceinline__ f32x4 mfma_f16(f16x8 a, f16x8 b, f32x4 c){
  return __builtin_amdgcn_mfma_f32_16x16x32_f16(a,b,c,0,0,0);
}
__device__ __forceinline__ f32x4 mfma_bf16(s16x8 a, s16x8 b, f32x4 c){
  return __builtin_amdgcn_mfma_f32_16x16x32_bf16(a,b,c,0,0,0);
}
__device__ __forceinline__ u16 f2bf(float v){
  unsigned u = __float_as_uint(v);
  unsigned r = u + 0x7fffu + ((u>>16)&1u);
  return (u16)(r>>16);
}
__device__ __forceinline__ float bf2f(u16 v){ return __uint_as_float(((unsigned)v)<<16); }

#define N_B 128

// ---- output offsets (f32 elements), reference return order ----
#define OUT_RECON 0
#define OUT_CODES 524288
#define OUT_LC    526336
#define OUT_NL    526339
#define OUT_NCT   8914947

// ---- workspace layout (BYTE offsets) ----
#define B_E1H  0ull
#define B_E1L  67108864ull
#define B_ZF   67108864ull              // [2048,256] f32 (2MiB)
#define B_ZQ4  69206016ull              // [2048,256] bf16 (1MiB)
#define B_ZSQ  70254592ull
#define B_ACC  70287360ull
#define B_CODES 70320128ull
#define B_H1   70385664ull              // 128KiB
#define B_H2   70516736ull              // 128KiB
#define B_H2B  70647808ull              // [128,256] bf16 (64KiB)
#define B_E3H  71303168ull              // 4MiB (alias D1)
#define B_E3L  75497472ull              // 4MiB (alias D2 head)
#define B_D1   71303168ull
#define B_D2   75497472ull              // 16MiB
#define B_EMB  92274688ull              // ~1.1MiB
#define B_ZFH  100663296ull             // [2048,256] f16 (1MiB)
#define B_ZFL  101711872ull             // (1MiB)
#define B_E2H  134217728ull
#define B_E2L  150994944ull
#define B_DOTS 134217728ull             // 32MiB aliases E2
#define B_WE2H 167772160ull             // packed weights, 2MiB each
#define B_WE2L 169869312ull
#define B_WE3H 171966464ull
#define B_WE3L 174063616ull
#define B_WE4H 176160768ull
#define B_WE4L 178257920ull
#define B_WD1  180355072ull
#define B_WD2  182452224ull
#define B_WD3  184549376ull
#define B_CBSQ 186646528ull
#define B_ZERO 186712064ull             // 512B zero guard
#define B_CBH  186712576ull             // packed codebook h (2MiB)
#define B_CBL  188809728ull             // packed codebook l (2MiB) -> end 190906880

// ---------- weight packing ----------
__global__ __launch_bounds__(256) void k_pack_enc(const float* __restrict__ w,
                                                  f16* __restrict__ Wh, f16* __restrict__ Wl){
  int o = blockIdx.x*256 + threadIdx.x;
  int j=o&7, l=(o>>3)&63, n=(o>>9)&15, icc=(o>>13)&7, tap=o>>16;
  int ic = icc*32 + (l>>4)*8 + j, oc = n*16 + (l&15);
  float v = w[((size_t)oc*256+ic)*16 + tap];
  f16 h = (f16)v;
  Wh[o]=h; Wl[o]=(f16)(v-(float)h);
}
__global__ __launch_bounds__(256) void k_pack_dec(const float* __restrict__ w, u16* __restrict__ Wp){
  int o = blockIdx.x*256 + threadIdx.x;
  int j=o&7, l=(o>>3)&63, n=(o>>9)&15, icc=(o>>13)&7, tap=o>>16;
  int ic = icc*32 + (l>>4)*8 + j, oc = n*16 + (l&15);
  Wp[o] = f2bf(w[((size_t)ic*256+oc)*16 + tap]);
}
__global__ __launch_bounds__(256) void k_pack_cb(const float* __restrict__ cb,
                                                 f16* __restrict__ H, f16* __restrict__ L){
  int s = blockIdx.x*256 + threadIdx.x;      // s = n*256 + k
  int n = s>>8, k = s&255;
  float v = cb[s];
  int nt = n>>4, lr2 = n&15, icc = k>>5, rr = k&31, lq2 = rr>>3, j = rr&7;
  size_t o = ((size_t)(nt*8+icc)*64 + lq2*16 + lr2)*8 + j;
  f16 h = (f16)v; H[o]=h; L[o]=(f16)(v-(float)h);
}
__global__ __launch_bounds__(256) void k_cbsq(const float* __restrict__ cb, float* __restrict__ cbsq,
                                              float* __restrict__ zg){
  int c = blockIdx.x*256 + threadIdx.x;
  if(blockIdx.x==0 && threadIdx.x<128) zg[threadIdx.x]=0.f;
  const float4* r4 = (const float4*)(cb + (size_t)c*256);
  float s = 0.f;
  for(int k=0;k<64;k++){ float4 v=r4[k]; s += v.x*v.x+v.y*v.y+v.z*v.z+v.w*v.w; }
  cbsq[c] = s;
}

// ---------- conv1: [B,1,64,64] f32 -> NHWC split-f16 [B,32,32,256] ----------
__global__ __launch_bounds__(256) void k_conv1(const float* __restrict__ x, const float* __restrict__ w1,
                                               const float* __restrict__ b1,
                                               f16* __restrict__ Oh, f16* __restrict__ Ol){
  int b = blockIdx.x >> 5, oy = blockIdx.x & 31;
  int oc = threadIdx.x;
  __shared__ float xs[4][68];
  for(int i=threadIdx.x;i<264;i+=256){
    int rr=i/66, cc=i-rr*66;
    int iy=2*oy-1+rr, ix=cc-1;
    float v=0.f;
    if((unsigned)iy<64u && (unsigned)ix<64u) v = x[((size_t)b*64+iy)*64+ix];
    xs[rr][cc]=v;
  }
  __syncthreads();
  float wv[16];
  #pragma unroll
  for(int k=0;k<16;k++) wv[k]=w1[oc*16+k];
  float bv=b1[oc];
  for(int ox=0;ox<32;ox++){
    float acc=bv;
    int c0=2*ox;
    #pragma unroll
    for(int kh=0;kh<4;kh++)
      #pragma unroll
      for(int kw=0;kw<4;kw++) acc += wv[kh*4+kw]*xs[kh][c0+kw];
    float v = fmaxf(acc,0.f);
    f16 h=(f16)v;
    size_t o = (((size_t)b*32+oy)*32+ox)*256+oc;
    Oh[o]=h; Ol[o]=(f16)(v-(float)h);
  }
}

// ---------- conv2 v7: 1024 thr, 4-way tap split x 4 n-quarters = 16 waves ----
// 2 blocks/CU -> 32 waves/CU = 8 waves/SIMD. Same staged window & weight
// traffic as v6; per-wave serial chain halves again. Group wg owns taps
// th=wg, tw=0..3. Partials summed via conflict-free f32x4 LDS reduction.
__global__ __launch_bounds__(1024,8) void k_conv_v7(
    const f16* __restrict__ Ah, const f16* __restrict__ Al,
    const f16* __restrict__ Wh, const f16* __restrict__ Wl,
    const float* __restrict__ bias, f16* __restrict__ Oh, f16* __restrict__ Ol){
  constexpr int HIN = 32, HOUT = 16, HH = 256;
  constexpr int ROWS = 64;
  constexpr int IYT = 10, IXT = 34, XS = 40;
  constexpr int RS  = IXT*XS;              // 1360
  constexpr int BUF = IYT*RS;              // 13600 halves
  constexpr int ITEMS = IYT*IXT*8;         // 2720
  __shared__ __align__(16) f16 As[2*BUF];  // 54400 B
  const int tid = threadIdx.x, lane = tid&63, w = tid>>6;
  const int wg = w>>2, wn = w&3;           // tap-group (th), n-quarter
  const int lr = lane&15, lq = lane>>4;
  const int m_base = blockIdx.x*ROWS;
  const int b = m_base/HH;
  const int oy0 = (m_base - b*HH)/HOUT;
  const int iy0 = 2*oy0 - 1;
  const size_t gimg = (size_t)b*HIN*HIN*256;

  // LDS read bases: fold th=wg row offset in
  int rbw[4];
  #pragma unroll
  for(int t=0;t<4;t++){
    int r = t*16 + lr;
    int oyl = r>>4, oxl = r&15;
    rbw[t] = (2*oyl + wg)*RS + (2*oxl)*XS + lq*8;
  }
  const size_t wgb = (size_t)wg*262144;    // 4 taps x 8 icc x 16 nt x 512

  f32x4 acc[4][4];
  #pragma unroll
  for(int t=0;t<4;t++)
    #pragma unroll
    for(int u=0;u<4;u++) acc[t][u] = (f32x4){0.f,0.f,0.f,0.f};

  for(int icc=0;icc<8;icc++){
    __syncthreads();
    for(int s=tid;s<ITEMS;s+=1024){
      int c = s&7, posi = s>>3;
      int hl = c>>2, ck = c&3;
      int iyl = posi/IXT, ixl = posi - iyl*IXT;
      int iy = iy0 + iyl, ix = ixl - 1;
      f16x8 v = {0,0,0,0,0,0,0,0};
      if((unsigned)iy<(unsigned)HIN && (unsigned)ix<(unsigned)HIN){
        const f16* src = (hl ? Al : Ah) + gimg + (size_t)(iy*HIN+ix)*256 + icc*32 + ck*8;
        v = *(const f16x8*)src;
      }
      *(f16x8*)&As[hl*BUF + iyl*RS + ixl*XS + ck*8] = v;
    }
    __syncthreads();
    #pragma unroll
    for(int tw=0;tw<4;tw++){
      f16x8 a_h[4], a_l[4];
      #pragma unroll
      for(int t=0;t<4;t++){
        int off = rbw[t] + tw*XS;
        a_h[t] = *(const f16x8*)&As[off];
        a_l[t] = *(const f16x8*)&As[BUF + off];
      }
      size_t wb = wgb + ((size_t)(tw*8+icc)*16 + wn*4)*512 + lane*8;
      #pragma unroll
      for(int u=0;u<4;u++){
        f16x8 b_h = *(const f16x8*)(Wh + wb + u*512);
        f16x8 b_l = *(const f16x8*)(Wl + wb + u*512);
        #pragma unroll
        for(int t=0;t<4;t++){
          acc[t][u] = mfma_f16(a_h[t], b_h, acc[t][u]);
          acc[t][u] = mfma_f16(a_h[t], b_l, acc[t][u]);
          acc[t][u] = mfma_f16(a_l[t], b_h, acc[t][u]);
        }
      }
    }
  }

  // ---- cross-group reduce: 4 rounds (one m-frag each), lane-contiguous f32x4
  f32x4* Rs = (f32x4*)As;                  // capacity 3400 f32x4
  const int rlane = wn*64 + lane;          // 0..255 within group
  #pragma unroll
  for(int mf=0;mf<4;mf++){
    __syncthreads();
    if(wg>0){
      #pragma unroll
      for(int u=0;u<4;u++) Rs[u*768 + (wg-1)*256 + rlane] = acc[mf][u];
    }
    __syncthreads();
    if(wg==0){
      #pragma unroll
      for(int u=0;u<4;u++){
        #pragma unroll
        for(int g=0;g<3;g++) acc[mf][u] += Rs[u*768 + g*256 + rlane];
      }
    }
  }
  if(wg==0){
    #pragma unroll
    for(int t=0;t<4;t++){
      #pragma unroll
      for(int u=0;u<4;u++){
        int n = (wn*4+u)*16 + lr;
        float bv = bias[n];
        #pragma unroll
        for(int r=0;r<4;r++){
          int m = m_base + t*16 + lq*4 + r;
          float v = fmaxf(acc[t][u][r] + bv, 0.f);
          size_t o = (size_t)m*256 + n;
          f16 h=(f16)v; Oh[o]=h; Ol[o]=(f16)(v-(float)h);
        }
      }
    }
  }
}

// ---------- conv3 v7: same 16-wave tap-split, ROWS=16, HIN=16 ----------
__global__ __launch_bounds__(1024,8) void k_conv3_v7(
    const f16* __restrict__ Ah, const f16* __restrict__ Al,
    const f16* __restrict__ Wh, const f16* __restrict__ Wl,
    const float* __restrict__ bias, f16* __restrict__ Oh, f16* __restrict__ Ol){
  constexpr int HIN = 16, HOUT = 8, HH = 64;
  constexpr int ROWS = 16;
  constexpr int IYT = 6, IXT = 18, XS = 40;
  constexpr int RS  = IXT*XS;              // 720
  constexpr int BUF = IYT*RS;              // 4320 halves
  constexpr int ITEMS = IYT*IXT*8;         // 864
  __shared__ __align__(16) f16 As[2*BUF];  // 17280 B
  const int tid = threadIdx.x, lane = tid&63, w = tid>>6;
  const int wg = w>>2, wn = w&3;
  const int lr = lane&15, lq = lane>>4;
  const int m_base = blockIdx.x*ROWS;
  const int b = m_base/HH;
  const int oy0 = (m_base - b*HH)/HOUT;
  const int iy0 = 2*oy0 - 1;
  const size_t gimg = (size_t)b*HIN*HIN*256;

  const int oyl = lr>>3, oxl = lr&7;
  const int rb = (2*oyl + wg)*RS + (2*oxl)*XS + lq*8;
  const size_t wgb = (size_t)wg*262144;

  f32x4 acc[4];
  #pragma unroll
  for(int u=0;u<4;u++) acc[u] = (f32x4){0.f,0.f,0.f,0.f};

  for(int icc=0;icc<8;icc++){
    __syncthreads();
    if(tid < ITEMS){
      int s = tid;
      int c = s&7, posi = s>>3;
      int hl = c>>2, ck = c&3;
      int iyl = posi/IXT, ixl = posi - iyl*IXT;
      int iy = iy0 + iyl, ix = ixl - 1;
      f16x8 v = {0,0,0,0,0,0,0,0};
      if((unsigned)iy<(unsigned)HIN && (unsigned)ix<(unsigned)HIN){
        const f16* src = (hl ? Al : Ah) + gimg + (size_t)(iy*HIN+ix)*256 + icc*32 + ck*8;
        v = *(const f16x8*)src;
      }
      *(f16x8*)&As[hl*BUF + iyl*RS + ixl*XS + ck*8] = v;
    }
    __syncthreads();
    #pragma unroll
    for(int tw=0;tw<4;tw++){
      int off = rb + tw*XS;
      f16x8 a_h = *(const f16x8*)&As[off];
      f16x8 a_l = *(const f16x8*)&As[BUF + off];
      size_t wb = wgb + ((size_t)(tw*8+icc)*16 + wn*4)*512 + lane*8;
      #pragma unroll
      for(int u=0;u<4;u++){
        f16x8 b_h = *(const f16x8*)(Wh + wb + u*512);
        f16x8 b_l = *(const f16x8*)(Wl + wb + u*512);
        acc[u] = mfma_f16(a_h, b_h, acc[u]);
        acc[u] = mfma_f16(a_h, b_l, acc[u]);
        acc[u] = mfma_f16(a_l, b_h, acc[u]);
      }
    }
  }

  // ---- cross-group reduce: 4 rounds (one u each); 768 f32x4 = 12KB <= LDS
  f32x4* Rs = (f32x4*)As;                  // capacity 1080 f32x4
  const int rlane = wn*64 + lane;
  #pragma unroll
  for(int u=0;u<4;u++){
    __syncthreads();
    if(wg>0) Rs[(wg-1)*256 + rlane] = acc[u];
    __syncthreads();
    if(wg==0){
      #pragma unroll
      for(int g=0;g<3;g++) acc[u] += Rs[g*256 + rlane];
    }
  }
  if(wg==0){
    #pragma unroll
    for(int u=0;u<4;u++){
      int n = (wn*4+u)*16 + lr;
      float bv = bias[n];
      #pragma unroll
      for(int r=0;r<4;r++){
        int m = m_base + lq*4 + r;
        float v = fmaxf(acc[u][r] + bv, 0.f);
        size_t o = (size_t)m*256 + n;
        f16 h=(f16)v; Oh[o]=h; Ol[o]=(f16)(v-(float)h);
      }
    }
  }
}

// ---------- legacy direct conv (conv4 only): f32 out + split-f16 zf ----------
template<int MT>
__global__ __launch_bounds__(256) void k_conv4(
    const f16* __restrict__ Ah, const f16* __restrict__ Al,
    const f16* __restrict__ Wh, const f16* __restrict__ Wl,
    const float* __restrict__ bias, float* __restrict__ Of,
    f16* __restrict__ Zh, f16* __restrict__ Zl,
    const f16* __restrict__ Zp, int Hin){
  const int Hout = Hin>>1, HH = Hout*Hout;
  const int lane = threadIdx.x & 63, w = threadIdx.x >> 6;
  const int lr = lane & 15, lq = lane >> 4;
  const int m_base = blockIdx.x * (16*MT);
  int iyb[MT], ixb[MT], bb[MT];
  #pragma unroll
  for(int t=0;t<MT;t++){
    int m = m_base + t*16 + lr;
    int b = m/HH, rem = m - b*HH;
    int oy = rem/Hout, ox = rem - oy*Hout;
    bb[t]=b; iyb[t]=2*oy-1; ixb[t]=2*ox-1;
  }
  f32x4 acc[MT][4];
  #pragma unroll
  for(int t=0;t<MT;t++)
    #pragma unroll
    for(int u=0;u<4;u++) acc[t][u]=(f32x4){0.f,0.f,0.f,0.f};

  for(int tap=0;tap<16;tap++){
    int th=tap>>2, tw=tap&3;
    const f16* pH[MT]; const f16* pL[MT];
    #pragma unroll
    for(int t=0;t<MT;t++){
      int iy=iyb[t]+th, ix=ixb[t]+tw;
      bool val = ((unsigned)iy<(unsigned)Hin) && ((unsigned)ix<(unsigned)Hin);
      size_t o = (((size_t)bb[t]*Hin+iy)*Hin+ix)*256 + lq*8;
      pH[t] = val ? Ah+o : Zp;
      pL[t] = val ? Al+o : Zp;
    }
    #pragma unroll
    for(int icc=0;icc<8;icc++){
      f16x8 a_h[MT], a_l[MT];
      #pragma unroll
      for(int t=0;t<MT;t++){
        a_h[t] = *(const f16x8*)(pH[t] + icc*32);
        a_l[t] = *(const f16x8*)(pL[t] + icc*32);
      }
      size_t wb = ((size_t)(tap*8+icc)*16 + w*4)*512 + lane*8;
      #pragma unroll
      for(int u=0;u<4;u++){
        f16x8 b_h = *(const f16x8*)(Wh + wb + u*512);
        f16x8 b_l = *(const f16x8*)(Wl + wb + u*512);
        #pragma unroll
        for(int t=0;t<MT;t++){
          acc[t][u] = mfma_f16(a_h[t], b_h, acc[t][u]);
          acc[t][u] = mfma_f16(a_h[t], b_l, acc[t][u]);
          acc[t][u] = mfma_f16(a_l[t], b_h, acc[t][u]);
        }
      }
    }
  }
  #pragma unroll
  for(int t=0;t<MT;t++){
    #pragma unroll
    for(int u=0;u<4;u++){
      int n = (w*4+u)*16 + lr;
      float bv = bias[n];
      #pragma unroll
      for(int r=0;r<4;r++){
        int m = m_base + t*16 + lq*4 + r;
        float v = acc[t][u][r] + bv;
        size_t o = (size_t)m*256 + n;
        Of[o]=v;
        f16 h=(f16)v; Zh[o]=h; Zl[o]=(f16)(v-(float)h);
      }
    }
  }
}

// ---------- decoder MFMA deconv (k4 s2 p1), parity-decomposed, bf16 ----------
template<int MT>
__global__ __launch_bounds__(256) void k_deconv_mfma(
    const u16* __restrict__ In, const u16* __restrict__ Wp,
    const float* __restrict__ bias, u16* __restrict__ Out,
    const u16* __restrict__ Zp, int H){
  const int Ho = H*2, HH = H*H;
  const int kh = blockIdx.y>>1, kw = blockIdx.y&1;
  const int lane = threadIdx.x & 63, w = threadIdx.x >> 6;
  const int lr = lane & 15, lq = lane >> 4;
  const int m_base = blockIdx.x * (16*MT);
  int jb[MT], ib[MT], bb[MT];
  #pragma unroll
  for(int t=0;t<MT;t++){
    int m = m_base + t*16 + lr;
    int b = m/HH, rem = m - b*HH;
    jb[t]=rem/H; ib[t]=rem-jb[t]*H; bb[t]=b;
  }
  f32x4 acc[MT][4];
  #pragma unroll
  for(int t=0;t<MT;t++)
    #pragma unroll
    for(int u=0;u<4;u++) acc[t][u]=(f32x4){0.f,0.f,0.f,0.f};

  #pragma unroll
  for(int dy=0;dy<2;dy++){
    #pragma unroll
    for(int dx=0;dx<2;dx++){
      int t16 = (kh+2*dy)*4 + (kw+2*dx);
      const u16* pA[MT];
      #pragma unroll
      for(int t=0;t<MT;t++){
        int r = jb[t]+(1-kh)-dy, c = ib[t]+(1-kw)-dx;
        bool val = ((unsigned)r<(unsigned)H) && ((unsigned)c<(unsigned)H);
        size_t o = (((size_t)bb[t]*H+r)*H+c)*256 + lq*8;
        pA[t] = val ? In+o : Zp;
      }
      #pragma unroll
      for(int icc=0;icc<8;icc++){
        s16x8 a[MT];
        #pragma unroll
        for(int t=0;t<MT;t++) a[t] = *(const s16x8*)(pA[t] + icc*32);
        size_t wb = ((size_t)(t16*8+icc)*16 + w*4)*512 + lane*8;
        #pragma unroll
        for(int u=0;u<4;u++){
          s16x8 bfr = *(const s16x8*)(Wp + wb + u*512);
          #pragma unroll
          for(int t=0;t<MT;t++) acc[t][u] = mfma_bf16(a[t], bfr, acc[t][u]);
        }
      }
    }
  }
  #pragma unroll
  for(int t=0;t<MT;t++){
    #pragma unroll
    for(int u=0;u<4;u++){
      int n = (w*4+u)*16 + lr;
      float bv = bias[n];
      #pragma unroll
      for(int r=0;r<4;r++){
        int m = m_base + t*16 + lq*4 + r;
        int b = m/HH, rem = m - b*HH;
        int j = rem/H, i = rem - j*H;
        int oy = 2*j + (1-kh), ox = 2*i + (1-kw);
        float v = fmaxf(acc[t][u][r] + bv, 0.f);
        Out[(((size_t)b*Ho+oy)*Ho+ox)*256 + n] = f2bf(v);
      }
    }
  }
}

// ---------- final deconv (OC=1) + sigmoid ----------
__global__ __launch_bounds__(256) void k_dec4(const u16* __restrict__ In, const float* __restrict__ w4,
                                              const float* __restrict__ bias, float* __restrict__ out){
  __shared__ float wt[16][256];
  int t = threadIdx.x;
  for(int i=t;i<4096;i+=256) wt[i&15][i>>4] = w4[i];
  __syncthreads();
  int ox = t & 63, oy = (blockIdx.x<<2) + (t>>6), b = blockIdx.y;
  int iyh=(oy+1)>>1, kh=(oy+1)&1;
  int ixh=(ox+1)>>1, kw=(ox+1)&1;
  float acc = bias[0];
  #pragma unroll
  for(int dy=0;dy<2;dy++){
    int r = iyh-dy;
    if((unsigned)r>=32u) continue;
    #pragma unroll
    for(int dx=0;dx<2;dx++){
      int c = ixh-dx;
      if((unsigned)c>=32u) continue;
      const u16* p = In + (((size_t)b*32+r)*32+c)*256;
      int widx = (kh+2*dy)*4 + kw+2*dx;
      float s=0.f;
      for(int ic=0;ic<256;ic+=8){
        s16x8 vv = *(const s16x8*)(p+ic);
        const float* wr = &wt[widx][ic];
        #pragma unroll
        for(int q=0;q<8;q++) s += bf2f((u16)vv[q])*wr[q];
      }
      acc += s;
    }
  }
  out[(size_t)b*4096 + oy*64 + ox] = 1.f/(1.f+__expf(-acc));
}

// ---------- zsq ----------
__global__ __launch_bounds__(256) void k_zsq(const float* __restrict__ zf, float* __restrict__ zsq){
  int r=blockIdx.x, c=threadIdx.x;
  float v = zf[(size_t)r*256+c];
  __shared__ float red[256];
  red[c]=v*v; __syncthreads();
  for(int s=128;s>0;s>>=1){ if(c<s) red[c]+=red[c+s]; __syncthreads(); }
  if(c==0) zsq[r]=red[0];
}

// ---------- VQ dots via split-f16 MFMA: D[2048][4096] = ZF * CB^T ----------
__global__ __launch_bounds__(256,2) void k_dots(
    const f16* __restrict__ ZH, const f16* __restrict__ ZL,
    const f16* __restrict__ CH, const f16* __restrict__ CL, float* __restrict__ D){
  const int lane = threadIdx.x & 63, w = threadIdx.x >> 6;
  const int lr = lane & 15, lq = lane >> 4;
  const int m_base = blockIdx.y*64, nb = blockIdx.x;
  f32x4 acc[4][4];
  #pragma unroll
  for(int t=0;t<4;t++)
    #pragma unroll
    for(int u=0;u<4;u++) acc[t][u]=(f32x4){0.f,0.f,0.f,0.f};
  #pragma unroll
  for(int icc=0;icc<8;icc++){
    f16x8 ah[4], al[4];
    #pragma unroll
    for(int t=0;t<4;t++){
      size_t o = (size_t)(m_base + t*16 + lr)*256 + lq*8 + icc*32;
      ah[t] = *(const f16x8*)(ZH+o);
      al[t] = *(const f16x8*)(ZL+o);
    }
    #pragma unroll
    for(int u=0;u<4;u++){
      int nt = nb*16 + w*4 + u;
      size_t wb = ((size_t)(nt*8+icc)*64 + lane)*8;
      f16x8 b_h = *(const f16x8*)(CH+wb);
      f16x8 b_l = *(const f16x8*)(CL+wb);
      #pragma unroll
      for(int t=0;t<4;t++){
        acc[t][u] = mfma_f16(ah[t], b_h, acc[t][u]);
        acc[t][u] = mfma_f16(ah[t], b_l, acc[t][u]);
        acc[t][u] = mfma_f16(al[t], b_h, acc[t][u]);
      }
    }
  }
  #pragma unroll
  for(int t=0;t<4;t++)
    #pragma unroll
    for(int u=0;u<4;u++){
      int n = nb*256 + (w*4+u)*16 + lr;
      #pragma unroll
      for(int r=0;r<4;r++){
        int m = m_base + t*16 + lq*4 + r;
        D[(size_t)m*4096 + n] = acc[t][u][r];
      }
    }
}

// ---------- VQ argmin ----------
__global__ __launch_bounds__(256) void k_argmin(const float* __restrict__ dots, const float* __restrict__ zsq,
                                                const float* __restrict__ cbsq, int* __restrict__ codes,
                                                float* __restrict__ out_codes){
  int r = blockIdx.x, t = threadIdx.x;
  float zs = zsq[r];
  float bv = 1e30f; int bi = 0x7fffffff;
  for(int c=t;c<4096;c+=256){
    float d = zs + cbsq[c] - 2.f*dots[(size_t)r*4096+c];
    if(d < bv || (d==bv && c<bi)){ bv=d; bi=c; }
  }
  __shared__ float sv[256]; __shared__ int si[256];
  sv[t]=bv; si[t]=bi; __syncthreads();
  for(int s=128;s>0;s>>=1){
    if(t<s){
      float v2=sv[t+s]; int i2=si[t+s];
      if(v2<sv[t] || (v2==sv[t] && i2<si[t])){ sv[t]=v2; si[t]=i2; }
    }
    __syncthreads();
  }
  if(t==0){ codes[r]=si[0]; out_codes[r]=(float)si[0]; }
}

__global__ void k_zero(float* a){ a[0]=0.f; }

// zq gather (bf16 NHWC) + loss accumulation
__global__ __launch_bounds__(256) void k_zqloss(const float* __restrict__ zf, const float* __restrict__ cb,
                                                const int* __restrict__ codes, u16* __restrict__ zq4,
                                                float* __restrict__ accum){
  int r = blockIdx.x, c = threadIdx.x;
  int code = codes[r];
  float q = cb[(size_t)code*256 + c];
  float d = zf[(size_t)r*256+c] - q;
  zq4[(size_t)r*256 + c] = f2bf(q);
  __shared__ float red[256];
  red[c]=d*d; __syncthreads();
  for(int s=128;s>0;s>>=1){ if(c<s) red[c]+=red[c+s]; __syncthreads(); }
  if(c==0) atomicAdd(accum, red[0]);
}

__global__ void k_final(const float* __restrict__ accum, float* __restrict__ out){
  if(threadIdx.x==0){
    float L = accum[0]*(1.f/524288.f);
    out[0]=L; out[1]=L; out[2]=1.25f*L;
  }
}

// ---------- dynamics ----------
__global__ __launch_bounds__(256) void k_embed(const int* __restrict__ codes, const int* __restrict__ action,
                                               const float* __restrict__ ce, const float* __restrict__ ae,
                                               float* __restrict__ emb){
  int b = blockIdx.x;
  for(int j=threadIdx.x;j<2176;j+=256){
    float v;
    if(j<2048){ int g=j>>7; v = ce[(size_t)codes[b*16+g]*128 + (j&127)]; }
    else      { v = ae[(size_t)action[b]*128 + (j-2048)]; }
    emb[(size_t)b*2176+j]=v;
  }
}

__global__ __launch_bounds__(256) void k_mlp(const float* __restrict__ in, const float* __restrict__ w,
                                             const float* __restrict__ bias, float* __restrict__ out,
                                             u16* __restrict__ outb, int K){
  int b = blockIdx.x, n = threadIdx.x;
  extern __shared__ float row[];
  for(int k=n;k<K;k+=256) row[k]=in[(size_t)b*K+k];
  __syncthreads();
  float acc = bias[n];
  for(int k=0;k<K;k++) acc += row[k]*w[(size_t)k*256+n];
  float v = fmaxf(acc,0.f);
  out[(size_t)b*256+n] = v;
  if(outb) outb[(size_t)b*256+n] = f2bf(v);
}

// ---------- dynamics head: [128,65536] = H2[128,256] @ W3 + b3, bf16 MFMA ----------
__global__ __launch_bounds__(256,2) void k_head(const u16* __restrict__ A,
                                                const float* __restrict__ w3,
                                                const float* __restrict__ b3,
                                                float* __restrict__ O){
  __shared__ u16 BS[8*64*8];                 // 8 n-tiles x 64 lanes x 8 = 8KB
  const int tid = threadIdx.x, lane = tid&63, w = tid>>6;
  const int lr = lane&15, lq = lane>>4;
  const int nb = blockIdx.x;                 // 512 blocks of n=128
  f32x4 acc[8][2];
  #pragma unroll
  for(int mt=0;mt<8;mt++)
    #pragma unroll
    for(int u=0;u<2;u++) acc[mt][u]=(f32x4){0.f,0.f,0.f,0.f};
  for(int icc=0;icc<8;icc++){
    __syncthreads();
    #pragma unroll
    for(int q=0;q<4;q++){
      int s = tid*16 + q*4;                  // [k=32][n=128] chunk, coalesced
      int kl = s>>7, nl = s&127;
      float4 v = *(const float4*)(w3 + (size_t)(icc*32+kl)*65536 + (size_t)nb*128 + nl);
      float vv[4] = {v.x,v.y,v.z,v.w};
      int j = kl&7, lqk = kl>>3;
      #pragma unroll
      for(int e=0;e<4;e++){
        int n2 = nl+e, ntl = n2>>4, lr2 = n2&15;
        BS[(ntl*64 + lqk*16 + lr2)*8 + j] = f2bf(vv[e]);
      }
    }
    __syncthreads();
    s16x8 a[8];
    #pragma unroll
    for(int mt=0;mt<8;mt++)
      a[mt] = *(const s16x8*)(A + (size_t)(mt*16+lr)*256 + icc*32 + lq*8);
    #pragma unroll
    for(int u=0;u<2;u++){
      int ntl = w*2+u;
      s16x8 bfr = *(const s16x8*)&BS[((size_t)ntl*64 + lane)*8];
      #pragma unroll
      for(int mt=0;mt<8;mt++) acc[mt][u] = mfma_bf16(a[mt], bfr, acc[mt][u]);
    }
  }
  #pragma unroll
  for(int mt=0;mt<8;mt++)
    #pragma unroll
    for(int u=0;u<2;u++){
      int n = nb*128 + (w*2+u)*16 + lr;
      float bv = b3[n];
      #pragma unroll
      for(int r=0;r<4;r++){
        int m = mt*16 + lq*4 + r;
        O[(size_t)m*65536 + n] = acc[mt][u][r] + bv;
      }
    }
}

extern "C" void kernel_launch(void* const* d_in, const int* in_sizes, int n_in,
                              void* d_out, int out_size, void* d_ws, size_t ws_size,
                              hipStream_t stream){
  (void)in_sizes; (void)n_in; (void)out_size; (void)ws_size;
  const float* x    = (const float*)d_in[0];
  const float* xn   = (const float*)d_in[1];
  const int*   act  = (const int*)  d_in[2];
  const float* ew1=(const float*)d_in[3];  const float* eb1=(const float*)d_in[4];
  const float* ew2=(const float*)d_in[5];  const float* eb2=(const float*)d_in[6];
  const float* ew3=(const float*)d_in[7];  const float* eb3=(const float*)d_in[8];
  const float* ew4=(const float*)d_in[9];  const float* eb4=(const float*)d_in[10];
  const float* dw1=(const float*)d_in[11]; const float* db1=(const float*)d_in[12];
  const float* dw2=(const float*)d_in[13]; const float* db2=(const float*)d_in[14];
  const float* dw3=(const float*)d_in[15]; const float* db3=(const float*)d_in[16];
  const float* dw4=(const float*)d_in[17]; const float* db4=(const float*)d_in[18];
  const float* cbk =(const float*)d_in[19];
  const float* cemb=(const float*)d_in[20];
  const float* aemb=(const float*)d_in[21];
  const float* yw1=(const float*)d_in[22]; const float* yb1=(const float*)d_in[23];
  const float* yw2=(const float*)d_in[24]; const float* yb2=(const float*)d_in[25];
  const float* yw3=(const float*)d_in[26]; const float* yb3=(const float*)d_in[27];
  float* out = (float*)d_out;

  char* wsb = (char*)d_ws;
  f16* E1H=(f16*)(wsb+B_E1H); f16* E1L=(f16*)(wsb+B_E1L);
  f16* E2H=(f16*)(wsb+B_E2H); f16* E2L=(f16*)(wsb+B_E2L);
  f16* E3H=(f16*)(wsb+B_E3H); f16* E3L=(f16*)(wsb+B_E3L);
  float* ZF=(float*)(wsb+B_ZF);
  f16* ZFH=(f16*)(wsb+B_ZFH); f16* ZFL=(f16*)(wsb+B_ZFL);
  u16* ZQ4=(u16*)(wsb+B_ZQ4);
  f16* WE2H=(f16*)(wsb+B_WE2H); f16* WE2L=(f16*)(wsb+B_WE2L);
  f16* WE3H=(f16*)(wsb+B_WE3H); f16* WE3L=(f16*)(wsb+B_WE3L);
  f16* WE4H=(f16*)(wsb+B_WE4H); f16* WE4L=(f16*)(wsb+B_WE4L);
  u16* WD1=(u16*)(wsb+B_WD1); u16* WD2=(u16*)(wsb+B_WD2); u16* WD3=(u16*)(wsb+B_WD3);
  f16* CBH=(f16*)(wsb+B_CBH); f16* CBL=(f16*)(wsb+B_CBL);
  float* ZSQ=(float*)(wsb+B_ZSQ); float* CBSQ=(float*)(wsb+B_CBSQ);
  float* EMB=(float*)(wsb+B_EMB); float* H1=(float*)(wsb+B_H1); float* H2=(float*)(wsb+B_H2);
  u16* H2B=(u16*)(wsb+B_H2B);
  float* ACC=(float*)(wsb+B_ACC); int* CODES=(int*)(wsb+B_CODES);
  float* ZG=(float*)(wsb+B_ZERO);
  const f16* Zf16=(const f16*)ZG; const u16* Zbf=(const u16*)ZG;
  float* DOTS=(float*)(wsb+B_DOTS);
  u16* D1=(u16*)(wsb+B_D1);
  u16* D2=(u16*)(wsb+B_D2);
  u16* D3=(u16*)(wsb+B_E1H);

  // weight prep
  k_pack_enc<<<4096,256,0,stream>>>(ew2, WE2H, WE2L);
  k_pack_enc<<<4096,256,0,stream>>>(ew3, WE3H, WE3L);
  k_pack_enc<<<4096,256,0,stream>>>(ew4, WE4H, WE4L);
  k_pack_dec<<<4096,256,0,stream>>>(dw1, WD1);
  k_pack_dec<<<4096,256,0,stream>>>(dw2, WD2);
  k_pack_dec<<<4096,256,0,stream>>>(dw3, WD3);
  k_pack_cb <<<4096,256,0,stream>>>(cbk, CBH, CBL);
  k_cbsq<<<16,256,0,stream>>>(cbk, CBSQ, ZG);

  auto encode = [&](const float* img, float* code_out){
    k_conv1<<<4096,256,0,stream>>>(img, ew1, eb1, E1H, E1L);
    k_conv_v7<<<512,1024,0,stream>>>(E1H,E1L, WE2H,WE2L, eb2, E2H,E2L);
    k_conv3_v7<<<512,1024,0,stream>>>(E2H,E2L, WE3H,WE3L, eb3, E3H,E3L);
    k_conv4<1><<<128,256,0,stream>>>(E3H,E3L, WE4H,WE4L, eb4, ZF, ZFH, ZFL, Zf16, 8);
    k_zsq<<<2048,256,0,stream>>>(ZF, ZSQ);
    k_dots<<<dim3(16,32),256,0,stream>>>(ZFH, ZFL, CBH, CBL, DOTS);
    k_argmin<<<2048,256,0,stream>>>(DOTS, ZSQ, CBSQ, CODES, code_out);
  };

  // ---- encode(x) + VQ ----
  encode(x, out+OUT_CODES);
  k_zero<<<1,1,0,stream>>>(ACC);
  k_zqloss<<<2048,256,0,stream>>>(ZF, cbk, CODES, ZQ4, ACC);
  k_final<<<1,64,0,stream>>>(ACC, out+OUT_LC);

  // ---- decoder (bf16 MFMA) ----
  k_deconv_mfma<1><<<dim3(128,4),256,0,stream>>>(ZQ4, WD1, db1, D1, Zbf, 4);
  k_deconv_mfma<4><<<dim3(128,4),256,0,stream>>>(D1,  WD2, db2, D2, Zbf, 8);
  k_deconv_mfma<4><<<dim3(512,4),256,0,stream>>>(D2,  WD3, db3, D3, Zbf, 16);
  k_dec4<<<dim3(16,N_B),256,0,stream>>>(D3, dw4, db4, out+OUT_RECON);

  // ---- dynamics ----
  k_embed<<<N_B,256,0,stream>>>(CODES, act, cemb, aemb, EMB);
  k_mlp<<<N_B,256,2176*4,stream>>>(EMB, yw1, yb1, H1, nullptr, 2176);
  k_mlp<<<N_B,256, 256*4,stream>>>(H1,  yw2, yb2, H2, H2B, 256);
  k_head<<<512,256,0,stream>>>(H2B, yw3, yb3, out+OUT_NL);

  // ---- encode(x_next) ----
  encode(xn, out+OUT_NCT);
}

// Round 7
// 1746.032 us; speedup vs baseline: 3.3620x; 3.3620x over previous
//
#include <hip/hip_runtime.h>
#include <hip/hip_bf16.h>

typedef _Float16 f16;
typedef f16   f16x8 __attribute__((ext_vector_type(8)));
typedef short s16x8 __attribute__((ext_vector_type(8)));
typedef float f32x4 __attribute__((ext_vector_type(4)));
typedef unsigned short u16;

__device__ __forceinline__ f32x4 mfma_f16(f16x8 a, f16x8 b, f32x4 c){
  return __builtin_amdgcn_mfma_f32_16x16x32_f16(a,b,c,0,0,0);
}
__device__ __forceinline__ f32x4 mfma_bf16(s16x8 a, s16x8 b, f32x4 c){
  return __builtin_amdgcn_mfma_f32_16x16x32_bf16(a,b,c,0,0,0);
}
__device__ __forceinline__ u16 f2bf(float v){
  unsigned u = __float_as_uint(v);
  unsigned r = u + 0x7fffu + ((u>>16)&1u);
  return (u16)(r>>16);
}
__device__ __forceinline__ float bf2f(u16 v){ return __uint_as_float(((unsigned)v)<<16); }

#define N_B 128

// ---- output offsets (f32 elements), reference return order ----
#define OUT_RECON 0
#define OUT_CODES 524288
#define OUT_LC    526336
#define OUT_NL    526339
#define OUT_NCT   8914947

// ---- workspace layout (BYTE offsets) ----
#define B_E1H  0ull
#define B_E1L  67108864ull
#define B_ZF   67108864ull              // [2048,256] f32 (2MiB)
#define B_ZQ4  69206016ull              // [2048,256] bf16 (1MiB)
#define B_ZSQ  70254592ull
#define B_ACC  70287360ull
#define B_CODES 70320128ull
#define B_H1   70385664ull              // 128KiB
#define B_H2   70516736ull              // 128KiB
#define B_H2B  70647808ull              // [128,256] bf16 (64KiB)
#define B_E3H  71303168ull              // 4MiB (alias D1)
#define B_E3L  75497472ull              // 4MiB (alias D2 head)
#define B_D1   71303168ull
#define B_D2   75497472ull              // 16MiB
#define B_EMB  92274688ull              // ~1.1MiB
#define B_ZFH  100663296ull             // [2048,256] f16 (1MiB)
#define B_ZFL  101711872ull             // (1MiB)
#define B_E2H  134217728ull
#define B_E2L  150994944ull
#define B_DOTS 134217728ull             // 32MiB aliases E2
#define B_WE2H 167772160ull             // packed weights, 2MiB each
#define B_WE2L 169869312ull
#define B_WE3H 171966464ull
#define B_WE3L 174063616ull
#define B_WE4H 176160768ull
#define B_WE4L 178257920ull
#define B_WD1  180355072ull
#define B_WD2  182452224ull
#define B_WD3  184549376ull
#define B_CBSQ 186646528ull
#define B_ZERO 186712064ull             // 512B zero guard
#define B_CBH  186712576ull             // packed codebook h (2MiB)
#define B_CBL  188809728ull             // packed codebook l (2MiB) -> end 190906880

// ---------- weight packing ----------
__global__ __launch_bounds__(256) void k_pack_enc(const float* __restrict__ w,
                                                  f16* __restrict__ Wh, f16* __restrict__ Wl){
  int o = blockIdx.x*256 + threadIdx.x;
  int j=o&7, l=(o>>3)&63, n=(o>>9)&15, icc=(o>>13)&7, tap=o>>16;
  int ic = icc*32 + (l>>4)*8 + j, oc = n*16 + (l&15);
  float v = w[((size_t)oc*256+ic)*16 + tap];
  f16 h = (f16)v;
  Wh[o]=h; Wl[o]=(f16)(v-(float)h);
}
__global__ __launch_bounds__(256) void k_pack_dec(const float* __restrict__ w, u16* __restrict__ Wp){
  int o = blockIdx.x*256 + threadIdx.x;
  int j=o&7, l=(o>>3)&63, n=(o>>9)&15, icc=(o>>13)&7, tap=o>>16;
  int ic = icc*32 + (l>>4)*8 + j, oc = n*16 + (l&15);
  Wp[o] = f2bf(w[((size_t)ic*256+oc)*16 + tap]);
}
__global__ __launch_bounds__(256) void k_pack_cb(const float* __restrict__ cb,
                                                 f16* __restrict__ H, f16* __restrict__ L){
  int s = blockIdx.x*256 + threadIdx.x;      // s = n*256 + k
  int n = s>>8, k = s&255;
  float v = cb[s];
  int nt = n>>4, lr2 = n&15, icc = k>>5, rr = k&31, lq2 = rr>>3, j = rr&7;
  size_t o = ((size_t)(nt*8+icc)*64 + lq2*16 + lr2)*8 + j;
  f16 h = (f16)v; H[o]=h; L[o]=(f16)(v-(float)h);
}
__global__ __launch_bounds__(256) void k_cbsq(const float* __restrict__ cb, float* __restrict__ cbsq,
                                              float* __restrict__ zg){
  int c = blockIdx.x*256 + threadIdx.x;
  if(blockIdx.x==0 && threadIdx.x<128) zg[threadIdx.x]=0.f;
  const float4* r4 = (const float4*)(cb + (size_t)c*256);
  float s = 0.f;
  for(int k=0;k<64;k++){ float4 v=r4[k]; s += v.x*v.x+v.y*v.y+v.z*v.z+v.w*v.w; }
  cbsq[c] = s;
}

// ---------- conv1: [B,1,64,64] f32 -> NHWC split-f16 [B,32,32,256] ----------
__global__ __launch_bounds__(256) void k_conv1(const float* __restrict__ x, const float* __restrict__ w1,
                                               const float* __restrict__ b1,
                                               f16* __restrict__ Oh, f16* __restrict__ Ol){
  int b = blockIdx.x >> 5, oy = blockIdx.x & 31;
  int oc = threadIdx.x;
  __shared__ float xs[4][68];
  for(int i=threadIdx.x;i<264;i+=256){
    int rr=i/66, cc=i-rr*66;
    int iy=2*oy-1+rr, ix=cc-1;
    float v=0.f;
    if((unsigned)iy<64u && (unsigned)ix<64u) v = x[((size_t)b*64+iy)*64+ix];
    xs[rr][cc]=v;
  }
  __syncthreads();
  float wv[16];
  #pragma unroll
  for(int k=0;k<16;k++) wv[k]=w1[oc*16+k];
  float bv=b1[oc];
  for(int ox=0;ox<32;ox++){
    float acc=bv;
    int c0=2*ox;
    #pragma unroll
    for(int kh=0;kh<4;kh++)
      #pragma unroll
      for(int kw=0;kw<4;kw++) acc += wv[kh*4+kw]*xs[kh][c0+kw];
    float v = fmaxf(acc,0.f);
    f16 h=(f16)v;
    size_t o = (((size_t)b*32+oy)*32+ox)*256+oc;
    Oh[o]=h; Ol[o]=(f16)(v-(float)h);
  }
}

// ---------- conv2 v6 (round-4 verified, 223us): tap-split 8-wave blocks ----------
// 512 thr: waves 0-3 compute taps 0-7, waves 4-7 taps 8-15, over the SAME staged
// window. Grid 512 -> 2 blocks/CU = 16 waves/CU = 4 waves/SIMD.
__global__ __launch_bounds__(512,4) void k_conv_v6(
    const f16* __restrict__ Ah, const f16* __restrict__ Al,
    const f16* __restrict__ Wh, const f16* __restrict__ Wl,
    const float* __restrict__ bias, f16* __restrict__ Oh, f16* __restrict__ Ol){
  constexpr int HIN = 32, HOUT = 16, HH = 256;
  constexpr int ROWS = 64;
  constexpr int IYT = 10, IXT = 34, XS = 40;
  constexpr int RS  = IXT*XS;              // 1360
  constexpr int BUF = IYT*RS;              // 13600 halves
  constexpr int ITEMS = IYT*IXT*8;         // 2720
  __shared__ __align__(16) f16 As[2*BUF];  // 54400 B
  const int tid = threadIdx.x, lane = tid&63, w = tid>>6;
  const int wg = w>>2, wn = w&3;           // tap-group, n-quarter
  const int lr = lane&15, lq = lane>>4;
  const int m_base = blockIdx.x*ROWS;
  const int b = m_base/HH;
  const int oy0 = (m_base - b*HH)/HOUT;
  const int iy0 = 2*oy0 - 1;
  const size_t gimg = (size_t)b*HIN*HIN*256;

  // LDS read bases: fold the group's tap-row offset (wg*2 rows) in
  int rbw[4];
  #pragma unroll
  for(int t=0;t<4;t++){
    int r = t*16 + lr;
    int oyl = r>>4, oxl = r&15;
    rbw[t] = (2*oyl + 2*wg)*RS + (2*oxl)*XS + lq*8;
  }
  const size_t wgb = (size_t)wg*524288;    // 8 taps x 8 icc x 16 nt x 512

  f32x4 acc[4][4];
  #pragma unroll
  for(int t=0;t<4;t++)
    #pragma unroll
    for(int u=0;u<4;u++) acc[t][u] = (f32x4){0.f,0.f,0.f,0.f};

  for(int icc=0;icc<8;icc++){
    __syncthreads();
    for(int s=tid;s<ITEMS;s+=512){
      int c = s&7, posi = s>>3;
      int hl = c>>2, ck = c&3;
      int iyl = posi/IXT, ixl = posi - iyl*IXT;
      int iy = iy0 + iyl, ix = ixl - 1;
      f16x8 v = {0,0,0,0,0,0,0,0};
      if((unsigned)iy<(unsigned)HIN && (unsigned)ix<(unsigned)HIN){
        const f16* src = (hl ? Al : Ah) + gimg + (size_t)(iy*HIN+ix)*256 + icc*32 + ck*8;
        v = *(const f16x8*)src;
      }
      *(f16x8*)&As[hl*BUF + iyl*RS + ixl*XS + ck*8] = v;
    }
    __syncthreads();
    #pragma unroll
    for(int tap8=0;tap8<8;tap8++){
      f16x8 a_h[4], a_l[4];
      #pragma unroll
      for(int t=0;t<4;t++){
        int off = rbw[t] + (tap8>>2)*RS + (tap8&3)*XS;
        a_h[t] = *(const f16x8*)&As[off];
        a_l[t] = *(const f16x8*)&As[BUF + off];
      }
      size_t wb = wgb + ((size_t)(tap8*8+icc)*16 + wn*4)*512 + lane*8;
      #pragma unroll
      for(int u=0;u<4;u++){
        f16x8 b_h = *(const f16x8*)(Wh + wb + u*512);
        f16x8 b_l = *(const f16x8*)(Wl + wb + u*512);
        #pragma unroll
        for(int t=0;t<4;t++){
          acc[t][u] = mfma_f16(a_h[t], b_h, acc[t][u]);
          acc[t][u] = mfma_f16(a_h[t], b_l, acc[t][u]);
          acc[t][u] = mfma_f16(a_l[t], b_h, acc[t][u]);
        }
      }
    }
  }

  // ---- cross-group reduce: wg1 partials -> wg0, 2 rounds of 32KB via LDS ----
  float* Rs = (float*)As;
  #pragma unroll
  for(int rr=0;rr<2;rr++){
    __syncthreads();
    if(wg==1){
      #pragma unroll
      for(int t2=0;t2<2;t2++)
        #pragma unroll
        for(int u=0;u<4;u++)
          *(f32x4*)&Rs[((wn*64+lane)*8 + t2*4 + u)*4] = acc[rr*2+t2][u];
    }
    __syncthreads();
    if(wg==0){
      #pragma unroll
      for(int t2=0;t2<2;t2++)
        #pragma unroll
        for(int u=0;u<4;u++){
          f32x4 o = *(const f32x4*)&Rs[((wn*64+lane)*8 + t2*4 + u)*4];
          acc[rr*2+t2][u] += o;
        }
    }
  }
  if(wg==0){
    #pragma unroll
    for(int t=0;t<4;t++){
      #pragma unroll
      for(int u=0;u<4;u++){
        int n = (wn*4+u)*16 + lr;
        float bv = bias[n];
        #pragma unroll
        for(int r=0;r<4;r++){
          int m = m_base + t*16 + lq*4 + r;
          float v = fmaxf(acc[t][u][r] + bv, 0.f);
          size_t o = (size_t)m*256 + n;
          f16 h=(f16)v; Oh[o]=h; Ol[o]=(f16)(v-(float)h);
        }
      }
    }
  }
}

// ---------- conv3 v6: same tap-split structure, ROWS=16, HIN=16 ----------
// 512 thr = 2 tap-groups x 4 n-quarters; grid 512 -> 2 blocks/CU = 4 waves/SIMD.
// acc[1][4] = 16 AGPRs/wave — light; launch_bounds(512,4) caps at 128 regs (safe).
__global__ __launch_bounds__(512,4) void k_conv3_v6(
    const f16* __restrict__ Ah, const f16* __restrict__ Al,
    const f16* __restrict__ Wh, const f16* __restrict__ Wl,
    const float* __restrict__ bias, f16* __restrict__ Oh, f16* __restrict__ Ol){
  constexpr int HIN = 16, HOUT = 8, HH = 64;
  constexpr int ROWS = 16;
  constexpr int IYT = 6, IXT = 18, XS = 40;
  constexpr int RS  = IXT*XS;              // 720
  constexpr int BUF = IYT*RS;              // 4320 halves
  constexpr int ITEMS = IYT*IXT*8;         // 864
  __shared__ __align__(16) f16 As[2*BUF];  // 17280 B
  const int tid = threadIdx.x, lane = tid&63, w = tid>>6;
  const int wg = w>>2, wn = w&3;           // tap-group (taps 8wg..8wg+7), n-quarter
  const int lr = lane&15, lq = lane>>4;
  const int m_base = blockIdx.x*ROWS;
  const int b = m_base/HH;
  const int oy0 = (m_base - b*HH)/HOUT;
  const int iy0 = 2*oy0 - 1;
  const size_t gimg = (size_t)b*HIN*HIN*256;

  const int oyl = lr>>3, oxl = lr&7;
  const int rb = (2*oyl + 2*wg)*RS + (2*oxl)*XS + lq*8;
  const size_t wgb = (size_t)wg*524288;    // 8 taps x 8 icc x 16 nt x 512

  f32x4 acc[4];
  #pragma unroll
  for(int u=0;u<4;u++) acc[u] = (f32x4){0.f,0.f,0.f,0.f};

  for(int icc=0;icc<8;icc++){
    __syncthreads();
    for(int s=tid;s<ITEMS;s+=512){
      int c = s&7, posi = s>>3;
      int hl = c>>2, ck = c&3;
      int iyl = posi/IXT, ixl = posi - iyl*IXT;
      int iy = iy0 + iyl, ix = ixl - 1;
      f16x8 v = {0,0,0,0,0,0,0,0};
      if((unsigned)iy<(unsigned)HIN && (unsigned)ix<(unsigned)HIN){
        const f16* src = (hl ? Al : Ah) + gimg + (size_t)(iy*HIN+ix)*256 + icc*32 + ck*8;
        v = *(const f16x8*)src;
      }
      *(f16x8*)&As[hl*BUF + iyl*RS + ixl*XS + ck*8] = v;
    }
    __syncthreads();
    #pragma unroll
    for(int tap8=0;tap8<8;tap8++){
      int off = rb + (tap8>>2)*RS + (tap8&3)*XS;
      f16x8 a_h = *(const f16x8*)&As[off];
      f16x8 a_l = *(const f16x8*)&As[BUF + off];
      size_t wb = wgb + ((size_t)(tap8*8+icc)*16 + wn*4)*512 + lane*8;
      #pragma unroll
      for(int u=0;u<4;u++){
        f16x8 b_h = *(const f16x8*)(Wh + wb + u*512);
        f16x8 b_l = *(const f16x8*)(Wl + wb + u*512);
        acc[u] = mfma_f16(a_h, b_h, acc[u]);
        acc[u] = mfma_f16(a_h, b_l, acc[u]);
        acc[u] = mfma_f16(a_l, b_h, acc[u]);
      }
    }
  }

  // ---- cross-group reduce: wg1 -> wg0, one round, conflict-free f32x4 ----
  f32x4* Rs = (f32x4*)As;                  // capacity 2160 f32x4; need 1024
  const int rlane = wn*64 + lane;
  __syncthreads();
  if(wg==1){
    #pragma unroll
    for(int u=0;u<4;u++) Rs[u*256 + rlane] = acc[u];
  }
  __syncthreads();
  if(wg==0){
    #pragma unroll
    for(int u=0;u<4;u++) acc[u] += Rs[u*256 + rlane];
    #pragma unroll
    for(int u=0;u<4;u++){
      int n = (wn*4+u)*16 + lr;
      float bv = bias[n];
      #pragma unroll
      for(int r=0;r<4;r++){
        int m = m_base + lq*4 + r;
        float v = fmaxf(acc[u][r] + bv, 0.f);
        size_t o = (size_t)m*256 + n;
        f16 h=(f16)v; Oh[o]=h; Ol[o]=(f16)(v-(float)h);
      }
    }
  }
}

// ---------- legacy direct conv (conv4 only): f32 out + split-f16 zf ----------
template<int MT>
__global__ __launch_bounds__(256) void k_conv4(
    const f16* __restrict__ Ah, const f16* __restrict__ Al,
    const f16* __restrict__ Wh, const f16* __restrict__ Wl,
    const float* __restrict__ bias, float* __restrict__ Of,
    f16* __restrict__ Zh, f16* __restrict__ Zl,
    const f16* __restrict__ Zp, int Hin){
  const int Hout = Hin>>1, HH = Hout*Hout;
  const int lane = threadIdx.x & 63, w = threadIdx.x >> 6;
  const int lr = lane & 15, lq = lane >> 4;
  const int m_base = blockIdx.x * (16*MT);
  int iyb[MT], ixb[MT], bb[MT];
  #pragma unroll
  for(int t=0;t<MT;t++){
    int m = m_base + t*16 + lr;
    int b = m/HH, rem = m - b*HH;
    int oy = rem/Hout, ox = rem - oy*Hout;
    bb[t]=b; iyb[t]=2*oy-1; ixb[t]=2*ox-1;
  }
  f32x4 acc[MT][4];
  #pragma unroll
  for(int t=0;t<MT;t++)
    #pragma unroll
    for(int u=0;u<4;u++) acc[t][u]=(f32x4){0.f,0.f,0.f,0.f};

  for(int tap=0;tap<16;tap++){
    int th=tap>>2, tw=tap&3;
    const f16* pH[MT]; const f16* pL[MT];
    #pragma unroll
    for(int t=0;t<MT;t++){
      int iy=iyb[t]+th, ix=ixb[t]+tw;
      bool val = ((unsigned)iy<(unsigned)Hin) && ((unsigned)ix<(unsigned)Hin);
      size_t o = (((size_t)bb[t]*Hin+iy)*Hin+ix)*256 + lq*8;
      pH[t] = val ? Ah+o : Zp;
      pL[t] = val ? Al+o : Zp;
    }
    #pragma unroll
    for(int icc=0;icc<8;icc++){
      f16x8 a_h[MT], a_l[MT];
      #pragma unroll
      for(int t=0;t<MT;t++){
        a_h[t] = *(const f16x8*)(pH[t] + icc*32);
        a_l[t] = *(const f16x8*)(pL[t] + icc*32);
      }
      size_t wb = ((size_t)(tap*8+icc)*16 + w*4)*512 + lane*8;
      #pragma unroll
      for(int u=0;u<4;u++){
        f16x8 b_h = *(const f16x8*)(Wh + wb + u*512);
        f16x8 b_l = *(const f16x8*)(Wl + wb + u*512);
        #pragma unroll
        for(int t=0;t<MT;t++){
          acc[t][u] = mfma_f16(a_h[t], b_h, acc[t][u]);
          acc[t][u] = mfma_f16(a_h[t], b_l, acc[t][u]);
          acc[t][u] = mfma_f16(a_l[t], b_h, acc[t][u]);
        }
      }
    }
  }
  #pragma unroll
  for(int t=0;t<MT;t++){
    #pragma unroll
    for(int u=0;u<4;u++){
      int n = (w*4+u)*16 + lr;
      float bv = bias[n];
      #pragma unroll
      for(int r=0;r<4;r++){
        int m = m_base + t*16 + lq*4 + r;
        float v = acc[t][u][r] + bv;
        size_t o = (size_t)m*256 + n;
        Of[o]=v;
        f16 h=(f16)v; Zh[o]=h; Zl[o]=(f16)(v-(float)h);
      }
    }
  }
}

// ---------- decoder MFMA deconv (k4 s2 p1), parity-decomposed, bf16 ----------
template<int MT>
__global__ __launch_bounds__(256) void k_deconv_mfma(
    const u16* __restrict__ In, const u16* __restrict__ Wp,
    const float* __restrict__ bias, u16* __restrict__ Out,
    const u16* __restrict__ Zp, int H){
  const int Ho = H*2, HH = H*H;
  const int kh = blockIdx.y>>1, kw = blockIdx.y&1;
  const int lane = threadIdx.x & 63, w = threadIdx.x >> 6;
  const int lr = lane & 15, lq = lane >> 4;
  const int m_base = blockIdx.x * (16*MT);
  int jb[MT], ib[MT], bb[MT];
  #pragma unroll
  for(int t=0;t<MT;t++){
    int m = m_base + t*16 + lr;
    int b = m/HH, rem = m - b*HH;
    jb[t]=rem/H; ib[t]=rem-jb[t]*H; bb[t]=b;
  }
  f32x4 acc[MT][4];
  #pragma unroll
  for(int t=0;t<MT;t++)
    #pragma unroll
    for(int u=0;u<4;u++) acc[t][u]=(f32x4){0.f,0.f,0.f,0.f};

  #pragma unroll
  for(int dy=0;dy<2;dy++){
    #pragma unroll
    for(int dx=0;dx<2;dx++){
      int t16 = (kh+2*dy)*4 + (kw+2*dx);
      const u16* pA[MT];
      #pragma unroll
      for(int t=0;t<MT;t++){
        int r = jb[t]+(1-kh)-dy, c = ib[t]+(1-kw)-dx;
        bool val = ((unsigned)r<(unsigned)H) && ((unsigned)c<(unsigned)H);
        size_t o = (((size_t)bb[t]*H+r)*H+c)*256 + lq*8;
        pA[t] = val ? In+o : Zp;
      }
      #pragma unroll
      for(int icc=0;icc<8;icc++){
        s16x8 a[MT];
        #pragma unroll
        for(int t=0;t<MT;t++) a[t] = *(const s16x8*)(pA[t] + icc*32);
        size_t wb = ((size_t)(t16*8+icc)*16 + w*4)*512 + lane*8;
        #pragma unroll
        for(int u=0;u<4;u++){
          s16x8 bfr = *(const s16x8*)(Wp + wb + u*512);
          #pragma unroll
          for(int t=0;t<MT;t++) acc[t][u] = mfma_bf16(a[t], bfr, acc[t][u]);
        }
      }
    }
  }
  #pragma unroll
  for(int t=0;t<MT;t++){
    #pragma unroll
    for(int u=0;u<4;u++){
      int n = (w*4+u)*16 + lr;
      float bv = bias[n];
      #pragma unroll
      for(int r=0;r<4;r++){
        int m = m_base + t*16 + lq*4 + r;
        int b = m/HH, rem = m - b*HH;
        int j = rem/H, i = rem - j*H;
        int oy = 2*j + (1-kh), ox = 2*i + (1-kw);
        float v = fmaxf(acc[t][u][r] + bv, 0.f);
        Out[(((size_t)b*Ho+oy)*Ho+ox)*256 + n] = f2bf(v);
      }
    }
  }
}

// ---------- final deconv (OC=1) + sigmoid ----------
__global__ __launch_bounds__(256) void k_dec4(const u16* __restrict__ In, const float* __restrict__ w4,
                                              const float* __restrict__ bias, float* __restrict__ out){
  __shared__ float wt[16][256];
  int t = threadIdx.x;
  for(int i=t;i<4096;i+=256) wt[i&15][i>>4] = w4[i];
  __syncthreads();
  int ox = t & 63, oy = (blockIdx.x<<2) + (t>>6), b = blockIdx.y;
  int iyh=(oy+1)>>1, kh=(oy+1)&1;
  int ixh=(ox+1)>>1, kw=(ox+1)&1;
  float acc = bias[0];
  #pragma unroll
  for(int dy=0;dy<2;dy++){
    int r = iyh-dy;
    if((unsigned)r>=32u) continue;
    #pragma unroll
    for(int dx=0;dx<2;dx++){
      int c = ixh-dx;
      if((unsigned)c>=32u) continue;
      const u16* p = In + (((size_t)b*32+r)*32+c)*256;
      int widx = (kh+2*dy)*4 + kw+2*dx;
      float s=0.f;
      for(int ic=0;ic<256;ic+=8){
        s16x8 vv = *(const s16x8*)(p+ic);
        const float* wr = &wt[widx][ic];
        #pragma unroll
        for(int q=0;q<8;q++) s += bf2f((u16)vv[q])*wr[q];
      }
      acc += s;
    }
  }
  out[(size_t)b*4096 + oy*64 + ox] = 1.f/(1.f+__expf(-acc));
}

// ---------- zsq ----------
__global__ __launch_bounds__(256) void k_zsq(const float* __restrict__ zf, float* __restrict__ zsq){
  int r=blockIdx.x, c=threadIdx.x;
  float v = zf[(size_t)r*256+c];
  __shared__ float red[256];
  red[c]=v*v; __syncthreads();
  for(int s=128;s>0;s>>=1){ if(c<s) red[c]+=red[c+s]; __syncthreads(); }
  if(c==0) zsq[r]=red[0];
}

// ---------- VQ dots via split-f16 MFMA: D[2048][4096] = ZF * CB^T ----------
__global__ __launch_bounds__(256,2) void k_dots(
    const f16* __restrict__ ZH, const f16* __restrict__ ZL,
    const f16* __restrict__ CH, const f16* __restrict__ CL, float* __restrict__ D){
  const int lane = threadIdx.x & 63, w = threadIdx.x >> 6;
  const int lr = lane & 15, lq = lane >> 4;
  const int m_base = blockIdx.y*64, nb = blockIdx.x;
  f32x4 acc[4][4];
  #pragma unroll
  for(int t=0;t<4;t++)
    #pragma unroll
    for(int u=0;u<4;u++) acc[t][u]=(f32x4){0.f,0.f,0.f,0.f};
  #pragma unroll
  for(int icc=0;icc<8;icc++){
    f16x8 ah[4], al[4];
    #pragma unroll
    for(int t=0;t<4;t++){
      size_t o = (size_t)(m_base + t*16 + lr)*256 + lq*8 + icc*32;
      ah[t] = *(const f16x8*)(ZH+o);
      al[t] = *(const f16x8*)(ZL+o);
    }
    #pragma unroll
    for(int u=0;u<4;u++){
      int nt = nb*16 + w*4 + u;
      size_t wb = ((size_t)(nt*8+icc)*64 + lane)*8;
      f16x8 b_h = *(const f16x8*)(CH+wb);
      f16x8 b_l = *(const f16x8*)(CL+wb);
      #pragma unroll
      for(int t=0;t<4;t++){
        acc[t][u] = mfma_f16(ah[t], b_h, acc[t][u]);
        acc[t][u] = mfma_f16(ah[t], b_l, acc[t][u]);
        acc[t][u] = mfma_f16(al[t], b_h, acc[t][u]);
      }
    }
  }
  #pragma unroll
  for(int t=0;t<4;t++)
    #pragma unroll
    for(int u=0;u<4;u++){
      int n = nb*256 + (w*4+u)*16 + lr;
      #pragma unroll
      for(int r=0;r<4;r++){
        int m = m_base + t*16 + lq*4 + r;
        D[(size_t)m*4096 + n] = acc[t][u][r];
      }
    }
}

// ---------- VQ argmin ----------
__global__ __launch_bounds__(256) void k_argmin(const float* __restrict__ dots, const float* __restrict__ zsq,
                                                const float* __restrict__ cbsq, int* __restrict__ codes,
                                                float* __restrict__ out_codes){
  int r = blockIdx.x, t = threadIdx.x;
  float zs = zsq[r];
  float bv = 1e30f; int bi = 0x7fffffff;
  for(int c=t;c<4096;c+=256){
    float d = zs + cbsq[c] - 2.f*dots[(size_t)r*4096+c];
    if(d < bv || (d==bv && c<bi)){ bv=d; bi=c; }
  }
  __shared__ float sv[256]; __shared__ int si[256];
  sv[t]=bv; si[t]=bi; __syncthreads();
  for(int s=128;s>0;s>>=1){
    if(t<s){
      float v2=sv[t+s]; int i2=si[t+s];
      if(v2<sv[t] || (v2==sv[t] && i2<si[t])){ sv[t]=v2; si[t]=i2; }
    }
    __syncthreads();
  }
  if(t==0){ codes[r]=si[0]; out_codes[r]=(float)si[0]; }
}

__global__ void k_zero(float* a){ a[0]=0.f; }

// zq gather (bf16 NHWC) + loss accumulation
__global__ __launch_bounds__(256) void k_zqloss(const float* __restrict__ zf, const float* __restrict__ cb,
                                                const int* __restrict__ codes, u16* __restrict__ zq4,
                                                float* __restrict__ accum){
  int r = blockIdx.x, c = threadIdx.x;
  int code = codes[r];
  float q = cb[(size_t)code*256 + c];
  float d = zf[(size_t)r*256+c] - q;
  zq4[(size_t)r*256 + c] = f2bf(q);
  __shared__ float red[256];
  red[c]=d*d; __syncthreads();
  for(int s=128;s>0;s>>=1){ if(c<s) red[c]+=red[c+s]; __syncthreads(); }
  if(c==0) atomicAdd(accum, red[0]);
}

__global__ void k_final(const float* __restrict__ accum, float* __restrict__ out){
  if(threadIdx.x==0){
    float L = accum[0]*(1.f/524288.f);
    out[0]=L; out[1]=L; out[2]=1.25f*L;
  }
}

// ---------- dynamics ----------
__global__ __launch_bounds__(256) void k_embed(const int* __restrict__ codes, const int* __restrict__ action,
                                               const float* __restrict__ ce, const float* __restrict__ ae,
                                               float* __restrict__ emb){
  int b = blockIdx.x;
  for(int j=threadIdx.x;j<2176;j+=256){
    float v;
    if(j<2048){ int g=j>>7; v = ce[(size_t)codes[b*16+g]*128 + (j&127)]; }
    else      { v = ae[(size_t)action[b]*128 + (j-2048)]; }
    emb[(size_t)b*2176+j]=v;
  }
}

__global__ __launch_bounds__(256) void k_mlp(const float* __restrict__ in, const float* __restrict__ w,
                                             const float* __restrict__ bias, float* __restrict__ out,
                                             u16* __restrict__ outb, int K){
  int b = blockIdx.x, n = threadIdx.x;
  extern __shared__ float row[];
  for(int k=n;k<K;k+=256) row[k]=in[(size_t)b*K+k];
  __syncthreads();
  float acc = bias[n];
  for(int k=0;k<K;k++) acc += row[k]*w[(size_t)k*256+n];
  float v = fmaxf(acc,0.f);
  out[(size_t)b*256+n] = v;
  if(outb) outb[(size_t)b*256+n] = f2bf(v);
}

// ---------- dynamics head: [128,65536] = H2[128,256] @ W3 + b3, bf16 MFMA ----------
__global__ __launch_bounds__(256,2) void k_head(const u16* __restrict__ A,
                                                const float* __restrict__ w3,
                                                const float* __restrict__ b3,
                                                float* __restrict__ O){
  __shared__ u16 BS[8*64*8];                 // 8 n-tiles x 64 lanes x 8 = 8KB
  const int tid = threadIdx.x, lane = tid&63, w = tid>>6;
  const int lr = lane&15, lq = lane>>4;
  const int nb = blockIdx.x;                 // 512 blocks of n=128
  f32x4 acc[8][2];
  #pragma unroll
  for(int mt=0;mt<8;mt++)
    #pragma unroll
    for(int u=0;u<2;u++) acc[mt][u]=(f32x4){0.f,0.f,0.f,0.f};
  for(int icc=0;icc<8;icc++){
    __syncthreads();
    #pragma unroll
    for(int q=0;q<4;q++){
      int s = tid*16 + q*4;                  // [k=32][n=128] chunk, coalesced
      int kl = s>>7, nl = s&127;
      float4 v = *(const float4*)(w3 + (size_t)(icc*32+kl)*65536 + (size_t)nb*128 + nl);
      float vv[4] = {v.x,v.y,v.z,v.w};
      int j = kl&7, lqk = kl>>3;
      #pragma unroll
      for(int e=0;e<4;e++){
        int n2 = nl+e, ntl = n2>>4, lr2 = n2&15;
        BS[(ntl*64 + lqk*16 + lr2)*8 + j] = f2bf(vv[e]);
      }
    }
    __syncthreads();
    s16x8 a[8];
    #pragma unroll
    for(int mt=0;mt<8;mt++)
      a[mt] = *(const s16x8*)(A + (size_t)(mt*16+lr)*256 + icc*32 + lq*8);
    #pragma unroll
    for(int u=0;u<2;u++){
      int ntl = w*2+u;
      s16x8 bfr = *(const s16x8*)&BS[((size_t)ntl*64 + lane)*8];
      #pragma unroll
      for(int mt=0;mt<8;mt++) acc[mt][u] = mfma_bf16(a[mt], bfr, acc[mt][u]);
    }
  }
  #pragma unroll
  for(int mt=0;mt<8;mt++)
    #pragma unroll
    for(int u=0;u<2;u++){
      int n = nb*128 + (w*2+u)*16 + lr;
      float bv = b3[n];
      #pragma unroll
      for(int r=0;r<4;r++){
        int m = mt*16 + lq*4 + r;
        O[(size_t)m*65536 + n] = acc[mt][u][r] + bv;
      }
    }
}

extern "C" void kernel_launch(void* const* d_in, const int* in_sizes, int n_in,
                              void* d_out, int out_size, void* d_ws, size_t ws_size,
                              hipStream_t stream){
  (void)in_sizes; (void)n_in; (void)out_size; (void)ws_size;
  const float* x    = (const float*)d_in[0];
  const float* xn   = (const float*)d_in[1];
  const int*   act  = (const int*)  d_in[2];
  const float* ew1=(const float*)d_in[3];  const float* eb1=(const float*)d_in[4];
  const float* ew2=(const float*)d_in[5];  const float* eb2=(const float*)d_in[6];
  const float* ew3=(const float*)d_in[7];  const float* eb3=(const float*)d_in[8];
  const float* ew4=(const float*)d_in[9];  const float* eb4=(const float*)d_in[10];
  const float* dw1=(const float*)d_in[11]; const float* db1=(const float*)d_in[12];
  const float* dw2=(const float*)d_in[13]; const float* db2=(const float*)d_in[14];
  const float* dw3=(const float*)d_in[15]; const float* db3=(const float*)d_in[16];
  const float* dw4=(const float*)d_in[17]; const float* db4=(const float*)d_in[18];
  const float* cbk =(const float*)d_in[19];
  const float* cemb=(const float*)d_in[20];
  const float* aemb=(const float*)d_in[21];
  const float* yw1=(const float*)d_in[22]; const float* yb1=(const float*)d_in[23];
  const float* yw2=(const float*)d_in[24]; const float* yb2=(const float*)d_in[25];
  const float* yw3=(const float*)d_in[26]; const float* yb3=(const float*)d_in[27];
  float* out = (float*)d_out;

  char* wsb = (char*)d_ws;
  f16* E1H=(f16*)(wsb+B_E1H); f16* E1L=(f16*)(wsb+B_E1L);
  f16* E2H=(f16*)(wsb+B_E2H); f16* E2L=(f16*)(wsb+B_E2L);
  f16* E3H=(f16*)(wsb+B_E3H); f16* E3L=(f16*)(wsb+B_E3L);
  float* ZF=(float*)(wsb+B_ZF);
  f16* ZFH=(f16*)(wsb+B_ZFH); f16* ZFL=(f16*)(wsb+B_ZFL);
  u16* ZQ4=(u16*)(wsb+B_ZQ4);
  f16* WE2H=(f16*)(wsb+B_WE2H); f16* WE2L=(f16*)(wsb+B_WE2L);
  f16* WE3H=(f16*)(wsb+B_WE3H); f16* WE3L=(f16*)(wsb+B_WE3L);
  f16* WE4H=(f16*)(wsb+B_WE4H); f16* WE4L=(f16*)(wsb+B_WE4L);
  u16* WD1=(u16*)(wsb+B_WD1); u16* WD2=(u16*)(wsb+B_WD2); u16* WD3=(u16*)(wsb+B_WD3);
  f16* CBH=(f16*)(wsb+B_CBH); f16* CBL=(f16*)(wsb+B_CBL);
  float* ZSQ=(float*)(wsb+B_ZSQ); float* CBSQ=(float*)(wsb+B_CBSQ);
  float* EMB=(float*)(wsb+B_EMB); float* H1=(float*)(wsb+B_H1); float* H2=(float*)(wsb+B_H2);
  u16* H2B=(u16*)(wsb+B_H2B);
  float* ACC=(float*)(wsb+B_ACC); int* CODES=(int*)(wsb+B_CODES);
  float* ZG=(float*)(wsb+B_ZERO);
  const f16* Zf16=(const f16*)ZG; const u16* Zbf=(const u16*)ZG;
  float* DOTS=(float*)(wsb+B_DOTS);
  u16* D1=(u16*)(wsb+B_D1);
  u16* D2=(u16*)(wsb+B_D2);
  u16* D3=(u16*)(wsb+B_E1H);

  // weight prep
  k_pack_enc<<<4096,256,0,stream>>>(ew2, WE2H, WE2L);
  k_pack_enc<<<4096,256,0,stream>>>(ew3, WE3H, WE3L);
  k_pack_enc<<<4096,256,0,stream>>>(ew4, WE4H, WE4L);
  k_pack_dec<<<4096,256,0,stream>>>(dw1, WD1);
  k_pack_dec<<<4096,256,0,stream>>>(dw2, WD2);
  k_pack_dec<<<4096,256,0,stream>>>(dw3, WD3);
  k_pack_cb <<<4096,256,0,stream>>>(cbk, CBH, CBL);
  k_cbsq<<<16,256,0,stream>>>(cbk, CBSQ, ZG);

  auto encode = [&](const float* img, float* code_out){
    k_conv1<<<4096,256,0,stream>>>(img, ew1, eb1, E1H, E1L);
    k_conv_v6<<<512,512,0,stream>>>(E1H,E1L, WE2H,WE2L, eb2, E2H,E2L);
    k_conv3_v6<<<512,512,0,stream>>>(E2H,E2L, WE3H,WE3L, eb3, E3H,E3L);
    k_conv4<1><<<128,256,0,stream>>>(E3H,E3L, WE4H,WE4L, eb4, ZF, ZFH, ZFL, Zf16, 8);
    k_zsq<<<2048,256,0,stream>>>(ZF, ZSQ);
    k_dots<<<dim3(16,32),256,0,stream>>>(ZFH, ZFL, CBH, CBL, DOTS);
    k_argmin<<<2048,256,0,stream>>>(DOTS, ZSQ, CBSQ, CODES, code_out);
  };

  // ---- encode(x) + VQ ----
  encode(x, out+OUT_CODES);
  k_zero<<<1,1,0,stream>>>(ACC);
  k_zqloss<<<2048,256,0,stream>>>(ZF, cbk, CODES, ZQ4, ACC);
  k_final<<<1,64,0,stream>>>(ACC, out+OUT_LC);

  // ---- decoder (bf16 MFMA) ----
  k_deconv_mfma<1><<<dim3(128,4),256,0,stream>>>(ZQ4, WD1, db1, D1, Zbf, 4);
  k_deconv_mfma<4><<<dim3(128,4),256,0,stream>>>(D1,  WD2, db2, D2, Zbf, 8);
  k_deconv_mfma<4><<<dim3(512,4),256,0,stream>>>(D2,  WD3, db3, D3, Zbf, 16);
  k_dec4<<<dim3(16,N_B),256,0,stream>>>(D3, dw4, db4, out+OUT_RECON);

  // ---- dynamics ----
  k_embed<<<N_B,256,0,stream>>>(CODES, act, cemb, aemb, EMB);
  k_mlp<<<N_B,256,2176*4,stream>>>(EMB, yw1, yb1, H1, nullptr, 2176);
  k_mlp<<<N_B,256, 256*4,stream>>>(H1,  yw2, yb2, H2, H2B, 256);
  k_head<<<512,256,0,stream>>>(H2B, yw3, yb3, out+OUT_NL);

  // ---- encode(x_next) ----
  encode(xn, out+OUT_NCT);
}

// Round 8
// 1630.744 us; speedup vs baseline: 3.5997x; 1.0707x over previous
//
#include <hip/hip_runtime.h>
#include <hip/hip_bf16.h>

typedef _Float16 f16;
typedef f16   f16x8 __attribute__((ext_vector_type(8)));
typedef short s16x8 __attribute__((ext_vector_type(8)));
typedef float f32x4 __attribute__((ext_vector_type(4)));
typedef unsigned short u16;

__device__ __forceinline__ f32x4 mfma_f16(f16x8 a, f16x8 b, f32x4 c){
  return __builtin_amdgcn_mfma_f32_16x16x32_f16(a,b,c,0,0,0);
}
__device__ __forceinline__ f32x4 mfma_bf16(s16x8 a, s16x8 b, f32x4 c){
  return __builtin_amdgcn_mfma_f32_16x16x32_bf16(a,b,c,0,0,0);
}
__device__ __forceinline__ u16 f2bf(float v){
  unsigned u = __float_as_uint(v);
  unsigned r = u + 0x7fffu + ((u>>16)&1u);
  return (u16)(r>>16);
}
__device__ __forceinline__ float bf2f(u16 v){ return __uint_as_float(((unsigned)v)<<16); }

#define N_B 128

// ---- output offsets (f32 elements), reference return order ----
#define OUT_RECON 0
#define OUT_CODES 524288
#define OUT_LC    526336
#define OUT_NL    526339
#define OUT_NCT   8914947

// ---- workspace layout (BYTE offsets) ----
#define B_E1H  0ull
#define B_E1L  67108864ull
#define B_ZF   67108864ull              // [2048,256] f32 (2MiB)
#define B_ZQ4  69206016ull              // [2048,256] bf16 (1MiB)
#define B_ZSQ  70254592ull
#define B_ACC  70287360ull
#define B_CODES 70320128ull
#define B_H1   70385664ull              // 128KiB
#define B_H2   70516736ull              // 128KiB
#define B_H2B  70647808ull              // [128,256] bf16 (64KiB)
#define B_E3H  71303168ull              // 4MiB (alias D1)
#define B_E3L  75497472ull              // 4MiB (alias D2 head)
#define B_D1   71303168ull
#define B_D2   75497472ull              // 16MiB
#define B_EMB  92274688ull              // ~1.1MiB
#define B_ZFH  100663296ull             // [2048,256] f16 (1MiB)
#define B_ZFL  101711872ull             // (1MiB)
#define B_E2H  134217728ull
#define B_E2L  150994944ull
#define B_DOTS 134217728ull             // 32MiB aliases E2
#define B_WE2H 167772160ull             // packed weights, 2MiB each
#define B_WE2L 169869312ull
#define B_WE3H 171966464ull
#define B_WE3L 174063616ull
#define B_WE4H 176160768ull
#define B_WE4L 178257920ull
#define B_WD1  180355072ull
#define B_WD2  182452224ull
#define B_WD3  184549376ull
#define B_CBSQ 186646528ull
#define B_ZERO 186712064ull             // 512B zero guard
#define B_CBH  186712576ull             // packed codebook h (2MiB)
#define B_CBL  188809728ull             // packed codebook l (2MiB) -> end 190906880

// ---------- weight packing ----------
__global__ __launch_bounds__(256) void k_pack_enc(const float* __restrict__ w,
                                                  f16* __restrict__ Wh, f16* __restrict__ Wl){
  int o = blockIdx.x*256 + threadIdx.x;
  int j=o&7, l=(o>>3)&63, n=(o>>9)&15, icc=(o>>13)&7, tap=o>>16;
  int ic = icc*32 + (l>>4)*8 + j, oc = n*16 + (l&15);
  float v = w[((size_t)oc*256+ic)*16 + tap];
  f16 h = (f16)v;
  Wh[o]=h; Wl[o]=(f16)(v-(float)h);
}
__global__ __launch_bounds__(256) void k_pack_dec(const float* __restrict__ w, u16* __restrict__ Wp){
  int o = blockIdx.x*256 + threadIdx.x;
  int j=o&7, l=(o>>3)&63, n=(o>>9)&15, icc=(o>>13)&7, tap=o>>16;
  int ic = icc*32 + (l>>4)*8 + j, oc = n*16 + (l&15);
  Wp[o] = f2bf(w[((size_t)ic*256+oc)*16 + tap]);
}
__global__ __launch_bounds__(256) void k_pack_cb(const float* __restrict__ cb,
                                                 f16* __restrict__ H, f16* __restrict__ L){
  int s = blockIdx.x*256 + threadIdx.x;      // s = n*256 + k
  int n = s>>8, k = s&255;
  float v = cb[s];
  int nt = n>>4, lr2 = n&15, icc = k>>5, rr = k&31, lq2 = rr>>3, j = rr&7;
  size_t o = ((size_t)(nt*8+icc)*64 + lq2*16 + lr2)*8 + j;
  f16 h = (f16)v; H[o]=h; L[o]=(f16)(v-(float)h);
}
__global__ __launch_bounds__(256) void k_cbsq(const float* __restrict__ cb, float* __restrict__ cbsq,
                                              float* __restrict__ zg){
  int c = blockIdx.x*256 + threadIdx.x;
  if(blockIdx.x==0 && threadIdx.x<128) zg[threadIdx.x]=0.f;
  const float4* r4 = (const float4*)(cb + (size_t)c*256);
  float s = 0.f;
  for(int k=0;k<64;k++){ float4 v=r4[k]; s += v.x*v.x+v.y*v.y+v.z*v.z+v.w*v.w; }
  cbsq[c] = s;
}

// ---------- conv1: [B,1,64,64] f32 -> NHWC split-f16 [B,32,32,256] ----------
__global__ __launch_bounds__(256) void k_conv1(const float* __restrict__ x, const float* __restrict__ w1,
                                               const float* __restrict__ b1,
                                               f16* __restrict__ Oh, f16* __restrict__ Ol){
  int b = blockIdx.x >> 5, oy = blockIdx.x & 31;
  int oc = threadIdx.x;
  __shared__ float xs[4][68];
  for(int i=threadIdx.x;i<264;i+=256){
    int rr=i/66, cc=i-rr*66;
    int iy=2*oy-1+rr, ix=cc-1;
    float v=0.f;
    if((unsigned)iy<64u && (unsigned)ix<64u) v = x[((size_t)b*64+iy)*64+ix];
    xs[rr][cc]=v;
  }
  __syncthreads();
  float wv[16];
  #pragma unroll
  for(int k=0;k<16;k++) wv[k]=w1[oc*16+k];
  float bv=b1[oc];
  for(int ox=0;ox<32;ox++){
    float acc=bv;
    int c0=2*ox;
    #pragma unroll
    for(int kh=0;kh<4;kh++)
      #pragma unroll
      for(int kw=0;kw<4;kw++) acc += wv[kh*4+kw]*xs[kh][c0+kw];
    float v = fmaxf(acc,0.f);
    f16 h=(f16)v;
    size_t o = (((size_t)b*32+oy)*32+ox)*256+oc;
    Oh[o]=h; Ol[o]=(f16)(v-(float)h);
  }
}

// ---------- conv2 v6nt: round-7 verified structure + nontemporal streaming ----
// Staging loads (E1 stream, no L2 reuse) and output stores are non-temporal so
// the 4MB packed weight set stays resident in the per-XCD L2 (it is exactly
// L2-sized); weight loads become L2 hits instead of L3/HBM.
__global__ __launch_bounds__(512,4) void k_conv_v6(
    const f16* __restrict__ Ah, const f16* __restrict__ Al,
    const f16* __restrict__ Wh, const f16* __restrict__ Wl,
    const float* __restrict__ bias, f16* __restrict__ Oh, f16* __restrict__ Ol){
  constexpr int HIN = 32, HOUT = 16, HH = 256;
  constexpr int ROWS = 64;
  constexpr int IYT = 10, IXT = 34, XS = 40;
  constexpr int RS  = IXT*XS;              // 1360
  constexpr int BUF = IYT*RS;              // 13600 halves
  constexpr int ITEMS = IYT*IXT*8;         // 2720
  __shared__ __align__(16) f16 As[2*BUF];  // 54400 B
  const int tid = threadIdx.x, lane = tid&63, w = tid>>6;
  const int wg = w>>2, wn = w&3;           // tap-group, n-quarter
  const int lr = lane&15, lq = lane>>4;
  const int m_base = blockIdx.x*ROWS;
  const int b = m_base/HH;
  const int oy0 = (m_base - b*HH)/HOUT;
  const int iy0 = 2*oy0 - 1;
  const size_t gimg = (size_t)b*HIN*HIN*256;

  int rbw[4];
  #pragma unroll
  for(int t=0;t<4;t++){
    int r = t*16 + lr;
    int oyl = r>>4, oxl = r&15;
    rbw[t] = (2*oyl + 2*wg)*RS + (2*oxl)*XS + lq*8;
  }
  const size_t wgb = (size_t)wg*524288;    // 8 taps x 8 icc x 16 nt x 512

  f32x4 acc[4][4];
  #pragma unroll
  for(int t=0;t<4;t++)
    #pragma unroll
    for(int u=0;u<4;u++) acc[t][u] = (f32x4){0.f,0.f,0.f,0.f};

  for(int icc=0;icc<8;icc++){
    __syncthreads();
    for(int s=tid;s<ITEMS;s+=512){
      int c = s&7, posi = s>>3;
      int hl = c>>2, ck = c&3;
      int iyl = posi/IXT, ixl = posi - iyl*IXT;
      int iy = iy0 + iyl, ix = ixl - 1;
      f16x8 v = {0,0,0,0,0,0,0,0};
      if((unsigned)iy<(unsigned)HIN && (unsigned)ix<(unsigned)HIN){
        const f16* src = (hl ? Al : Ah) + gimg + (size_t)(iy*HIN+ix)*256 + icc*32 + ck*8;
        v = __builtin_nontemporal_load((const f16x8*)src);
      }
      *(f16x8*)&As[hl*BUF + iyl*RS + ixl*XS + ck*8] = v;
    }
    __syncthreads();
    #pragma unroll
    for(int tap8=0;tap8<8;tap8++){
      f16x8 a_h[4], a_l[4];
      #pragma unroll
      for(int t=0;t<4;t++){
        int off = rbw[t] + (tap8>>2)*RS + (tap8&3)*XS;
        a_h[t] = *(const f16x8*)&As[off];
        a_l[t] = *(const f16x8*)&As[BUF + off];
      }
      size_t wb = wgb + ((size_t)(tap8*8+icc)*16 + wn*4)*512 + lane*8;
      #pragma unroll
      for(int u=0;u<4;u++){
        f16x8 b_h = *(const f16x8*)(Wh + wb + u*512);
        f16x8 b_l = *(const f16x8*)(Wl + wb + u*512);
        #pragma unroll
        for(int t=0;t<4;t++){
          acc[t][u] = mfma_f16(a_h[t], b_h, acc[t][u]);
          acc[t][u] = mfma_f16(a_h[t], b_l, acc[t][u]);
          acc[t][u] = mfma_f16(a_l[t], b_h, acc[t][u]);
        }
      }
    }
  }

  // ---- cross-group reduce: wg1 partials -> wg0, 2 rounds of 32KB via LDS ----
  float* Rs = (float*)As;
  #pragma unroll
  for(int rr=0;rr<2;rr++){
    __syncthreads();
    if(wg==1){
      #pragma unroll
      for(int t2=0;t2<2;t2++)
        #pragma unroll
        for(int u=0;u<4;u++)
          *(f32x4*)&Rs[((wn*64+lane)*8 + t2*4 + u)*4] = acc[rr*2+t2][u];
    }
    __syncthreads();
    if(wg==0){
      #pragma unroll
      for(int t2=0;t2<2;t2++)
        #pragma unroll
        for(int u=0;u<4;u++){
          f32x4 o = *(const f32x4*)&Rs[((wn*64+lane)*8 + t2*4 + u)*4];
          acc[rr*2+t2][u] += o;
        }
    }
  }
  if(wg==0){
    #pragma unroll
    for(int t=0;t<4;t++){
      #pragma unroll
      for(int u=0;u<4;u++){
        int n = (wn*4+u)*16 + lr;
        float bv = bias[n];
        #pragma unroll
        for(int r=0;r<4;r++){
          int m = m_base + t*16 + lq*4 + r;
          float v = fmaxf(acc[t][u][r] + bv, 0.f);
          size_t o = (size_t)m*256 + n;
          f16 h=(f16)v;
          __builtin_nontemporal_store(h, &Oh[o]);
          __builtin_nontemporal_store((f16)(v-(float)h), &Ol[o]);
        }
      }
    }
  }
}

// ---------- conv3 v6nt: same structure, ROWS=16, HIN=16, nt streaming ----------
__global__ __launch_bounds__(512,4) void k_conv3_v6(
    const f16* __restrict__ Ah, const f16* __restrict__ Al,
    const f16* __restrict__ Wh, const f16* __restrict__ Wl,
    const float* __restrict__ bias, f16* __restrict__ Oh, f16* __restrict__ Ol){
  constexpr int HIN = 16, HOUT = 8, HH = 64;
  constexpr int ROWS = 16;
  constexpr int IYT = 6, IXT = 18, XS = 40;
  constexpr int RS  = IXT*XS;              // 720
  constexpr int BUF = IYT*RS;              // 4320 halves
  constexpr int ITEMS = IYT*IXT*8;         // 864
  __shared__ __align__(16) f16 As[2*BUF];  // 17280 B
  const int tid = threadIdx.x, lane = tid&63, w = tid>>6;
  const int wg = w>>2, wn = w&3;
  const int lr = lane&15, lq = lane>>4;
  const int m_base = blockIdx.x*ROWS;
  const int b = m_base/HH;
  const int oy0 = (m_base - b*HH)/HOUT;
  const int iy0 = 2*oy0 - 1;
  const size_t gimg = (size_t)b*HIN*HIN*256;

  const int oyl = lr>>3, oxl = lr&7;
  const int rb = (2*oyl + 2*wg)*RS + (2*oxl)*XS + lq*8;
  const size_t wgb = (size_t)wg*524288;

  f32x4 acc[4];
  #pragma unroll
  for(int u=0;u<4;u++) acc[u] = (f32x4){0.f,0.f,0.f,0.f};

  for(int icc=0;icc<8;icc++){
    __syncthreads();
    for(int s=tid;s<ITEMS;s+=512){
      int c = s&7, posi = s>>3;
      int hl = c>>2, ck = c&3;
      int iyl = posi/IXT, ixl = posi - iyl*IXT;
      int iy = iy0 + iyl, ix = ixl - 1;
      f16x8 v = {0,0,0,0,0,0,0,0};
      if((unsigned)iy<(unsigned)HIN && (unsigned)ix<(unsigned)HIN){
        const f16* src = (hl ? Al : Ah) + gimg + (size_t)(iy*HIN+ix)*256 + icc*32 + ck*8;
        v = __builtin_nontemporal_load((const f16x8*)src);
      }
      *(f16x8*)&As[hl*BUF + iyl*RS + ixl*XS + ck*8] = v;
    }
    __syncthreads();
    #pragma unroll
    for(int tap8=0;tap8<8;tap8++){
      int off = rb + (tap8>>2)*RS + (tap8&3)*XS;
      f16x8 a_h = *(const f16x8*)&As[off];
      f16x8 a_l = *(const f16x8*)&As[BUF + off];
      size_t wb = wgb + ((size_t)(tap8*8+icc)*16 + wn*4)*512 + lane*8;
      #pragma unroll
      for(int u=0;u<4;u++){
        f16x8 b_h = *(const f16x8*)(Wh + wb + u*512);
        f16x8 b_l = *(const f16x8*)(Wl + wb + u*512);
        acc[u] = mfma_f16(a_h, b_h, acc[u]);
        acc[u] = mfma_f16(a_h, b_l, acc[u]);
        acc[u] = mfma_f16(a_l, b_h, acc[u]);
      }
    }
  }

  // ---- cross-group reduce: wg1 -> wg0, one round, conflict-free f32x4 ----
  f32x4* Rs = (f32x4*)As;                  // capacity 2160 f32x4; need 1024
  const int rlane = wn*64 + lane;
  __syncthreads();
  if(wg==1){
    #pragma unroll
    for(int u=0;u<4;u++) Rs[u*256 + rlane] = acc[u];
  }
  __syncthreads();
  if(wg==0){
    #pragma unroll
    for(int u=0;u<4;u++) acc[u] += Rs[u*256 + rlane];
    #pragma unroll
    for(int u=0;u<4;u++){
      int n = (wn*4+u)*16 + lr;
      float bv = bias[n];
      #pragma unroll
      for(int r=0;r<4;r++){
        int m = m_base + lq*4 + r;
        float v = fmaxf(acc[u][r] + bv, 0.f);
        size_t o = (size_t)m*256 + n;
        f16 h=(f16)v;
        __builtin_nontemporal_store(h, &Oh[o]);
        __builtin_nontemporal_store((f16)(v-(float)h), &Ol[o]);
      }
    }
  }
}

// ---------- conv4 v6: tap+n split, full-GPU grid dim3(128,2) x 512 thr ----------
// Hin=8 fixed. 8 waves = 2 tap-groups x 4 n-pairs; each wave: 1 m-frag x 2 u.
// Was 128 blocks x 256 thr (half the CUs idle); now every CU has 8 waves.
__global__ __launch_bounds__(512,4) void k_conv4_v6(
    const f16* __restrict__ Ah, const f16* __restrict__ Al,
    const f16* __restrict__ Wh, const f16* __restrict__ Wl,
    const float* __restrict__ bias, float* __restrict__ Of,
    f16* __restrict__ Zh, f16* __restrict__ Zl,
    const f16* __restrict__ Zp){
  constexpr int HIN = 8, HOUT = 4, HH = 16;
  __shared__ f32x4 Red[512];               // 8KB
  const int tid = threadIdx.x, lane = tid&63, w = tid>>6;
  const int wg = w>>2, wn = w&3;           // tap-group, n-pair
  const int lr = lane&15, lq = lane>>4;
  const int mt = blockIdx.x;               // 0..127 m-tile
  const int ny = blockIdx.y;               // 0..1 n-half
  const int m = mt*16 + lr;
  const int b = m>>4, rem = m&15;
  const int oy = rem>>2, ox = rem&3;
  const int iyb = 2*oy-1, ixb = 2*ox-1;

  f32x4 acc[2];
  acc[0]=(f32x4){0.f,0.f,0.f,0.f}; acc[1]=(f32x4){0.f,0.f,0.f,0.f};

  #pragma unroll
  for(int tap8=0;tap8<8;tap8++){
    const int tap = wg*8 + tap8;
    const int th = tap>>2, tw = tap&3;
    int iy = iyb+th, ix = ixb+tw;
    bool val = ((unsigned)iy<(unsigned)HIN) && ((unsigned)ix<(unsigned)HIN);
    size_t o = (((size_t)b*HIN+iy)*HIN+ix)*256 + lq*8;
    const f16* pH = val ? Ah+o : Zp;
    const f16* pL = val ? Al+o : Zp;
    #pragma unroll
    for(int icc=0;icc<8;icc++){
      f16x8 a_h = *(const f16x8*)(pH + icc*32);
      f16x8 a_l = *(const f16x8*)(pL + icc*32);
      size_t wb = ((size_t)(tap*8+icc)*16 + ny*8 + wn*2)*512 + lane*8;
      #pragma unroll
      for(int u=0;u<2;u++){
        f16x8 b_h = *(const f16x8*)(Wh + wb + u*512);
        f16x8 b_l = *(const f16x8*)(Wl + wb + u*512);
        acc[u] = mfma_f16(a_h, b_h, acc[u]);
        acc[u] = mfma_f16(a_h, b_l, acc[u]);
        acc[u] = mfma_f16(a_l, b_h, acc[u]);
      }
    }
  }

  const int rl = wn*64 + lane;             // 0..255
  __syncthreads();
  if(wg==1){
    Red[0*256+rl] = acc[0];
    Red[1*256+rl] = acc[1];
  }
  __syncthreads();
  if(wg==0){
    acc[0] += Red[0*256+rl];
    acc[1] += Red[1*256+rl];
    #pragma unroll
    for(int u=0;u<2;u++){
      int n = ny*128 + (wn*2+u)*16 + lr;
      float bv = bias[n];
      #pragma unroll
      for(int r=0;r<4;r++){
        int m2 = mt*16 + lq*4 + r;
        float v = acc[u][r] + bv;
        size_t o = (size_t)m2*256 + n;
        Of[o]=v;
        f16 h=(f16)v; Zh[o]=h; Zl[o]=(f16)(v-(float)h);
      }
    }
  }
}

// ---------- decoder MFMA deconv (k4 s2 p1), parity-decomposed, bf16 ----------
template<int MT>
__global__ __launch_bounds__(256) void k_deconv_mfma(
    const u16* __restrict__ In, const u16* __restrict__ Wp,
    const float* __restrict__ bias, u16* __restrict__ Out,
    const u16* __restrict__ Zp, int H){
  const int Ho = H*2, HH = H*H;
  const int kh = blockIdx.y>>1, kw = blockIdx.y&1;
  const int lane = threadIdx.x & 63, w = threadIdx.x >> 6;
  const int lr = lane & 15, lq = lane >> 4;
  const int m_base = blockIdx.x * (16*MT);
  int jb[MT], ib[MT], bb[MT];
  #pragma unroll
  for(int t=0;t<MT;t++){
    int m = m_base + t*16 + lr;
    int b = m/HH, rem = m - b*HH;
    jb[t]=rem/H; ib[t]=rem-jb[t]*H; bb[t]=b;
  }
  f32x4 acc[MT][4];
  #pragma unroll
  for(int t=0;t<MT;t++)
    #pragma unroll
    for(int u=0;u<4;u++) acc[t][u]=(f32x4){0.f,0.f,0.f,0.f};

  #pragma unroll
  for(int dy=0;dy<2;dy++){
    #pragma unroll
    for(int dx=0;dx<2;dx++){
      int t16 = (kh+2*dy)*4 + (kw+2*dx);
      const u16* pA[MT];
      #pragma unroll
      for(int t=0;t<MT;t++){
        int r = jb[t]+(1-kh)-dy, c = ib[t]+(1-kw)-dx;
        bool val = ((unsigned)r<(unsigned)H) && ((unsigned)c<(unsigned)H);
        size_t o = (((size_t)bb[t]*H+r)*H+c)*256 + lq*8;
        pA[t] = val ? In+o : Zp;
      }
      #pragma unroll
      for(int icc=0;icc<8;icc++){
        s16x8 a[MT];
        #pragma unroll
        for(int t=0;t<MT;t++) a[t] = *(const s16x8*)(pA[t] + icc*32);
        size_t wb = ((size_t)(t16*8+icc)*16 + w*4)*512 + lane*8;
        #pragma unroll
        for(int u=0;u<4;u++){
          s16x8 bfr = *(const s16x8*)(Wp + wb + u*512);
          #pragma unroll
          for(int t=0;t<MT;t++) acc[t][u] = mfma_bf16(a[t], bfr, acc[t][u]);
        }
      }
    }
  }
  #pragma unroll
  for(int t=0;t<MT;t++){
    #pragma unroll
    for(int u=0;u<4;u++){
      int n = (w*4+u)*16 + lr;
      float bv = bias[n];
      #pragma unroll
      for(int r=0;r<4;r++){
        int m = m_base + t*16 + lq*4 + r;
        int b = m/HH, rem = m - b*HH;
        int j = rem/H, i = rem - j*H;
        int oy = 2*j + (1-kh), ox = 2*i + (1-kw);
        float v = fmaxf(acc[t][u][r] + bv, 0.f);
        Out[(((size_t)b*Ho+oy)*Ho+ox)*256 + n] = f2bf(v);
      }
    }
  }
}

// ---------- final deconv (OC=1) + sigmoid ----------
__global__ __launch_bounds__(256) void k_dec4(const u16* __restrict__ In, const float* __restrict__ w4,
                                              const float* __restrict__ bias, float* __restrict__ out){
  __shared__ float wt[16][256];
  int t = threadIdx.x;
  for(int i=t;i<4096;i+=256) wt[i&15][i>>4] = w4[i];
  __syncthreads();
  int ox = t & 63, oy = (blockIdx.x<<2) + (t>>6), b = blockIdx.y;
  int iyh=(oy+1)>>1, kh=(oy+1)&1;
  int ixh=(ox+1)>>1, kw=(ox+1)&1;
  float acc = bias[0];
  #pragma unroll
  for(int dy=0;dy<2;dy++){
    int r = iyh-dy;
    if((unsigned)r>=32u) continue;
    #pragma unroll
    for(int dx=0;dx<2;dx++){
      int c = ixh-dx;
      if((unsigned)c>=32u) continue;
      const u16* p = In + (((size_t)b*32+r)*32+c)*256;
      int widx = (kh+2*dy)*4 + kw+2*dx;
      float s=0.f;
      for(int ic=0;ic<256;ic+=8){
        s16x8 vv = *(const s16x8*)(p+ic);
        const float* wr = &wt[widx][ic];
        #pragma unroll
        for(int q=0;q<8;q++) s += bf2f((u16)vv[q])*wr[q];
      }
      acc += s;
    }
  }
  out[(size_t)b*4096 + oy*64 + ox] = 1.f/(1.f+__expf(-acc));
}

// ---------- zsq ----------
__global__ __launch_bounds__(256) void k_zsq(const float* __restrict__ zf, float* __restrict__ zsq){
  int r=blockIdx.x, c=threadIdx.x;
  float v = zf[(size_t)r*256+c];
  __shared__ float red[256];
  red[c]=v*v; __syncthreads();
  for(int s=128;s>0;s>>=1){ if(c<s) red[c]+=red[c+s]; __syncthreads(); }
  if(c==0) zsq[r]=red[0];
}

// ---------- VQ dots via split-f16 MFMA: D[2048][4096] = ZF * CB^T ----------
__global__ __launch_bounds__(256,2) void k_dots(
    const f16* __restrict__ ZH, const f16* __restrict__ ZL,
    const f16* __restrict__ CH, const f16* __restrict__ CL, float* __restrict__ D){
  const int lane = threadIdx.x & 63, w = threadIdx.x >> 6;
  const int lr = lane & 15, lq = lane >> 4;
  const int m_base = blockIdx.y*64, nb = blockIdx.x;
  f32x4 acc[4][4];
  #pragma unroll
  for(int t=0;t<4;t++)
    #pragma unroll
    for(int u=0;u<4;u++) acc[t][u]=(f32x4){0.f,0.f,0.f,0.f};
  #pragma unroll
  for(int icc=0;icc<8;icc++){
    f16x8 ah[4], al[4];
    #pragma unroll
    for(int t=0;t<4;t++){
      size_t o = (size_t)(m_base + t*16 + lr)*256 + lq*8 + icc*32;
      ah[t] = *(const f16x8*)(ZH+o);
      al[t] = *(const f16x8*)(ZL+o);
    }
    #pragma unroll
    for(int u=0;u<4;u++){
      int nt = nb*16 + w*4 + u;
      size_t wb = ((size_t)(nt*8+icc)*64 + lane)*8;
      f16x8 b_h = *(const f16x8*)(CH+wb);
      f16x8 b_l = *(const f16x8*)(CL+wb);
      #pragma unroll
      for(int t=0;t<4;t++){
        acc[t][u] = mfma_f16(ah[t], b_h, acc[t][u]);
        acc[t][u] = mfma_f16(ah[t], b_l, acc[t][u]);
        acc[t][u] = mfma_f16(al[t], b_h, acc[t][u]);
      }
    }
  }
  #pragma unroll
  for(int t=0;t<4;t++)
    #pragma unroll
    for(int u=0;u<4;u++){
      int n = nb*256 + (w*4+u)*16 + lr;
      #pragma unroll
      for(int r=0;r<4;r++){
        int m = m_base + t*16 + lq*4 + r;
        D[(size_t)m*4096 + n] = acc[t][u][r];
      }
    }
}

// ---------- VQ argmin ----------
__global__ __launch_bounds__(256) void k_argmin(const float* __restrict__ dots, const float* __restrict__ zsq,
                                                const float* __restrict__ cbsq, int* __restrict__ codes,
                                                float* __restrict__ out_codes){
  int r = blockIdx.x, t = threadIdx.x;
  float zs = zsq[r];
  float bv = 1e30f; int bi = 0x7fffffff;
  for(int c=t;c<4096;c+=256){
    float d = zs + cbsq[c] - 2.f*dots[(size_t)r*4096+c];
    if(d < bv || (d==bv && c<bi)){ bv=d; bi=c; }
  }
  __shared__ float sv[256]; __shared__ int si[256];
  sv[t]=bv; si[t]=bi; __syncthreads();
  for(int s=128;s>0;s>>=1){
    if(t<s){
      float v2=sv[t+s]; int i2=si[t+s];
      if(v2<sv[t] || (v2==sv[t] && i2<si[t])){ sv[t]=v2; si[t]=i2; }
    }
    __syncthreads();
  }
  if(t==0){ codes[r]=si[0]; out_codes[r]=(float)si[0]; }
}

__global__ void k_zero(float* a){ a[0]=0.f; }

// zq gather (bf16 NHWC) + loss accumulation
__global__ __launch_bounds__(256) void k_zqloss(const float* __restrict__ zf, const float* __restrict__ cb,
                                                const int* __restrict__ codes, u16* __restrict__ zq4,
                                                float* __restrict__ accum){
  int r = blockIdx.x, c = threadIdx.x;
  int code = codes[r];
  float q = cb[(size_t)code*256 + c];
  float d = zf[(size_t)r*256+c] - q;
  zq4[(size_t)r*256 + c] = f2bf(q);
  __shared__ float red[256];
  red[c]=d*d; __syncthreads();
  for(int s=128;s>0;s>>=1){ if(c<s) red[c]+=red[c+s]; __syncthreads(); }
  if(c==0) atomicAdd(accum, red[0]);
}

__global__ void k_final(const float* __restrict__ accum, float* __restrict__ out){
  if(threadIdx.x==0){
    float L = accum[0]*(1.f/524288.f);
    out[0]=L; out[1]=L; out[2]=1.25f*L;
  }
}

// ---------- dynamics ----------
__global__ __launch_bounds__(256) void k_embed(const int* __restrict__ codes, const int* __restrict__ action,
                                               const float* __restrict__ ce, const float* __restrict__ ae,
                                               float* __restrict__ emb){
  int b = blockIdx.x;
  for(int j=threadIdx.x;j<2176;j+=256){
    float v;
    if(j<2048){ int g=j>>7; v = ce[(size_t)codes[b*16+g]*128 + (j&127)]; }
    else      { v = ae[(size_t)action[b]*128 + (j-2048)]; }
    emb[(size_t)b*2176+j]=v;
  }
}

__global__ __launch_bounds__(256) void k_mlp(const float* __restrict__ in, const float* __restrict__ w,
                                             const float* __restrict__ bias, float* __restrict__ out,
                                             u16* __restrict__ outb, int K){
  int b = blockIdx.x, n = threadIdx.x;
  extern __shared__ float row[];
  for(int k=n;k<K;k+=256) row[k]=in[(size_t)b*K+k];
  __syncthreads();
  float acc = bias[n];
  for(int k=0;k<K;k++) acc += row[k]*w[(size_t)k*256+n];
  float v = fmaxf(acc,0.f);
  out[(size_t)b*256+n] = v;
  if(outb) outb[(size_t)b*256+n] = f2bf(v);
}

// ---------- dynamics head: [128,65536] = H2[128,256] @ W3 + b3, bf16 MFMA ----------
__global__ __launch_bounds__(256,2) void k_head(const u16* __restrict__ A,
                                                const float* __restrict__ w3,
                                                const float* __restrict__ b3,
                                                float* __restrict__ O){
  __shared__ u16 BS[8*64*8];                 // 8 n-tiles x 64 lanes x 8 = 8KB
  const int tid = threadIdx.x, lane = tid&63, w = tid>>6;
  const int lr = lane&15, lq = lane>>4;
  const int nb = blockIdx.x;                 // 512 blocks of n=128
  f32x4 acc[8][2];
  #pragma unroll
  for(int mt=0;mt<8;mt++)
    #pragma unroll
    for(int u=0;u<2;u++) acc[mt][u]=(f32x4){0.f,0.f,0.f,0.f};
  for(int icc=0;icc<8;icc++){
    __syncthreads();
    #pragma unroll
    for(int q=0;q<4;q++){
      int s = tid*16 + q*4;                  // [k=32][n=128] chunk, coalesced
      int kl = s>>7, nl = s&127;
      float4 v = *(const float4*)(w3 + (size_t)(icc*32+kl)*65536 + (size_t)nb*128 + nl);
      float vv[4] = {v.x,v.y,v.z,v.w};
      int j = kl&7, lqk = kl>>3;
      #pragma unroll
      for(int e=0;e<4;e++){
        int n2 = nl+e, ntl = n2>>4, lr2 = n2&15;
        BS[(ntl*64 + lqk*16 + lr2)*8 + j] = f2bf(vv[e]);
      }
    }
    __syncthreads();
    s16x8 a[8];
    #pragma unroll
    for(int mt=0;mt<8;mt++)
      a[mt] = *(const s16x8*)(A + (size_t)(mt*16+lr)*256 + icc*32 + lq*8);
    #pragma unroll
    for(int u=0;u<2;u++){
      int ntl = w*2+u;
      s16x8 bfr = *(const s16x8*)&BS[((size_t)ntl*64 + lane)*8];
      #pragma unroll
      for(int mt=0;mt<8;mt++) acc[mt][u] = mfma_bf16(a[mt], bfr, acc[mt][u]);
    }
  }
  #pragma unroll
  for(int mt=0;mt<8;mt++)
    #pragma unroll
    for(int u=0;u<2;u++){
      int n = nb*128 + (w*2+u)*16 + lr;
      float bv = b3[n];
      #pragma unroll
      for(int r=0;r<4;r++){
        int m = mt*16 + lq*4 + r;
        O[(size_t)m*65536 + n] = acc[mt][u][r] + bv;
      }
    }
}

extern "C" void kernel_launch(void* const* d_in, const int* in_sizes, int n_in,
                              void* d_out, int out_size, void* d_ws, size_t ws_size,
                              hipStream_t stream){
  (void)in_sizes; (void)n_in; (void)out_size; (void)ws_size;
  const float* x    = (const float*)d_in[0];
  const float* xn   = (const float*)d_in[1];
  const int*   act  = (const int*)  d_in[2];
  const float* ew1=(const float*)d_in[3];  const float* eb1=(const float*)d_in[4];
  const float* ew2=(const float*)d_in[5];  const float* eb2=(const float*)d_in[6];
  const float* ew3=(const float*)d_in[7];  const float* eb3=(const float*)d_in[8];
  const float* ew4=(const float*)d_in[9];  const float* eb4=(const float*)d_in[10];
  const float* dw1=(const float*)d_in[11]; const float* db1=(const float*)d_in[12];
  const float* dw2=(const float*)d_in[13]; const float* db2=(const float*)d_in[14];
  const float* dw3=(const float*)d_in[15]; const float* db3=(const float*)d_in[16];
  const float* dw4=(const float*)d_in[17]; const float* db4=(const float*)d_in[18];
  const float* cbk =(const float*)d_in[19];
  const float* cemb=(const float*)d_in[20];
  const float* aemb=(const float*)d_in[21];
  const float* yw1=(const float*)d_in[22]; const float* yb1=(const float*)d_in[23];
  const float* yw2=(const float*)d_in[24]; const float* yb2=(const float*)d_in[25];
  const float* yw3=(const float*)d_in[26]; const float* yb3=(const float*)d_in[27];
  float* out = (float*)d_out;

  char* wsb = (char*)d_ws;
  f16* E1H=(f16*)(wsb+B_E1H); f16* E1L=(f16*)(wsb+B_E1L);
  f16* E2H=(f16*)(wsb+B_E2H); f16* E2L=(f16*)(wsb+B_E2L);
  f16* E3H=(f16*)(wsb+B_E3H); f16* E3L=(f16*)(wsb+B_E3L);
  float* ZF=(float*)(wsb+B_ZF);
  f16* ZFH=(f16*)(wsb+B_ZFH); f16* ZFL=(f16*)(wsb+B_ZFL);
  u16* ZQ4=(u16*)(wsb+B_ZQ4);
  f16* WE2H=(f16*)(wsb+B_WE2H); f16* WE2L=(f16*)(wsb+B_WE2L);
  f16* WE3H=(f16*)(wsb+B_WE3H); f16* WE3L=(f16*)(wsb+B_WE3L);
  f16* WE4H=(f16*)(wsb+B_WE4H); f16* WE4L=(f16*)(wsb+B_WE4L);
  u16* WD1=(u16*)(wsb+B_WD1); u16* WD2=(u16*)(wsb+B_WD2); u16* WD3=(u16*)(wsb+B_WD3);
  f16* CBH=(f16*)(wsb+B_CBH); f16* CBL=(f16*)(wsb+B_CBL);
  float* ZSQ=(float*)(wsb+B_ZSQ); float* CBSQ=(float*)(wsb+B_CBSQ);
  float* EMB=(float*)(wsb+B_EMB); float* H1=(float*)(wsb+B_H1); float* H2=(float*)(wsb+B_H2);
  u16* H2B=(u16*)(wsb+B_H2B);
  float* ACC=(float*)(wsb+B_ACC); int* CODES=(int*)(wsb+B_CODES);
  float* ZG=(float*)(wsb+B_ZERO);
  const f16* Zf16=(const f16*)ZG; const u16* Zbf=(const u16*)ZG;
  float* DOTS=(float*)(wsb+B_DOTS);
  u16* D1=(u16*)(wsb+B_D1);
  u16* D2=(u16*)(wsb+B_D2);
  u16* D3=(u16*)(wsb+B_E1H);

  // weight prep
  k_pack_enc<<<4096,256,0,stream>>>(ew2, WE2H, WE2L);
  k_pack_enc<<<4096,256,0,stream>>>(ew3, WE3H, WE3L);
  k_pack_enc<<<4096,256,0,stream>>>(ew4, WE4H, WE4L);
  k_pack_dec<<<4096,256,0,stream>>>(dw1, WD1);
  k_pack_dec<<<4096,256,0,stream>>>(dw2, WD2);
  k_pack_dec<<<4096,256,0,stream>>>(dw3, WD3);
  k_pack_cb <<<4096,256,0,stream>>>(cbk, CBH, CBL);
  k_cbsq<<<16,256,0,stream>>>(cbk, CBSQ, ZG);

  auto encode = [&](const float* img, float* code_out){
    k_conv1<<<4096,256,0,stream>>>(img, ew1, eb1, E1H, E1L);
    k_conv_v6<<<512,512,0,stream>>>(E1H,E1L, WE2H,WE2L, eb2, E2H,E2L);
    k_conv3_v6<<<512,512,0,stream>>>(E2H,E2L, WE3H,WE3L, eb3, E3H,E3L);
    k_conv4_v6<<<dim3(128,2),512,0,stream>>>(E3H,E3L, WE4H,WE4L, eb4, ZF, ZFH, ZFL, Zf16);
    k_zsq<<<2048,256,0,stream>>>(ZF, ZSQ);
    k_dots<<<dim3(16,32),256,0,stream>>>(ZFH, ZFL, CBH, CBL, DOTS);
    k_argmin<<<2048,256,0,stream>>>(DOTS, ZSQ, CBSQ, CODES, code_out);
  };

  // ---- encode(x) + VQ ----
  encode(x, out+OUT_CODES);
  k_zero<<<1,1,0,stream>>>(ACC);
  k_zqloss<<<2048,256,0,stream>>>(ZF, cbk, CODES, ZQ4, ACC);
  k_final<<<1,64,0,stream>>>(ACC, out+OUT_LC);

  // ---- decoder (bf16 MFMA) ----
  k_deconv_mfma<1><<<dim3(128,4),256,0,stream>>>(ZQ4, WD1, db1, D1, Zbf, 4);
  k_deconv_mfma<4><<<dim3(128,4),256,0,stream>>>(D1,  WD2, db2, D2, Zbf, 8);
  k_deconv_mfma<4><<<dim3(512,4),256,0,stream>>>(D2,  WD3, db3, D3, Zbf, 16);
  k_dec4<<<dim3(16,N_B),256,0,stream>>>(D3, dw4, db4, out+OUT_RECON);

  // ---- dynamics ----
  k_embed<<<N_B,256,0,stream>>>(CODES, act, cemb, aemb, EMB);
  k_mlp<<<N_B,256,2176*4,stream>>>(EMB, yw1, yb1, H1, nullptr, 2176);
  k_mlp<<<N_B,256, 256*4,stream>>>(H1,  yw2, yb2, H2, H2B, 256);
  k_head<<<512,256,0,stream>>>(H2B, yw3, yb3, out+OUT_NL);

  // ---- encode(x_next) ----
  encode(xn, out+OUT_NCT);
}